// Round 2
// baseline (3876.043 us; speedup 1.0000x reference)
//
#include <hip/hip_runtime.h>
#include <hip/hip_bf16.h>
#include <cstddef>

// ---------------- problem constants ----------------
#define HEADS   4
#define C2c     384
#define HDc     96
#define HPc     63
#define WPc     63
#define NWc     81
#define NTOKc   49
#define BATCH   8
#define TOKP    (BATCH*HPc*WPc)   // 31752 padded tokens (windowed rows)
#define TOKC    (BATCH*60*60)     // 28800 cropped tokens
#define MLPH    1536
#define CONVK   3456              // 384*9
#define TPB     3969              // tokens (windowed rows) per batch = 81*49

// ---------------- block reduce (384 threads, 6 waves) ----------------
__device__ __forceinline__ float2 block_reduce_384(float v, float* red) {
  __syncthreads();                       // protect red reuse across calls
  float s = v, q = v * v;
  #pragma unroll
  for (int o = 32; o > 0; o >>= 1) {
    s += __shfl_down(s, o);
    q += __shfl_down(q, o);
  }
  int w = threadIdx.x >> 6;
  if ((threadIdx.x & 63) == 0) { red[2*w] = s; red[2*w+1] = q; }
  __syncthreads();
  float ts = red[0]+red[2]+red[4]+red[6]+red[8]+red[10];
  float tq = red[1]+red[3]+red[5]+red[7]+red[9]+red[11];
  return make_float2(ts, tq);
}

// ---------------- K1: concat+pad -> LN(norm) -> z(cropped) ; LN(n1)+roll+window -> wbuf ----------------
__global__ __launch_bounds__(384)
void build_ln_kernel(const float* __restrict__ x, const float* __restrict__ g,
                     const float* __restrict__ nw, const float* __restrict__ nb,
                     const float* __restrict__ n1w, const float* __restrict__ n1b,
                     float* __restrict__ z, float* __restrict__ wbuf)
{
  __shared__ float red[12];
  int t = blockIdx.x;                 // padded token id
  int b = t / (HPc*WPc);
  int rem = t - b*(HPc*WPc);
  int i = rem / WPc, j = rem - (rem / WPc)*WPc;
  int c = threadIdx.x;

  float v = 0.f;
  if (i < 60 && j < 60) {
    if (c < 192) v = x[(((size_t)b*192 + c)*60 + i)*60 + j];
    else         v = g[(((size_t)b*192 + (c-192))*60 + i)*60 + j];
  }
  // LN1 (norm)
  float2 ss = block_reduce_384(v, red);
  float mu  = ss.x * (1.f/384.f);
  float var = ss.y * (1.f/384.f) - mu*mu;
  float zi  = (v - mu) * rsqrtf(var + 1e-5f) * nw[c] + nb[c];
  if (i < 60 && j < 60)
    z[(((size_t)b*60 + i)*60 + j)*C2c + c] = zi;   // cropped residual store
  // LN2 (n1)
  float2 s2 = block_reduce_384(zi, red);
  float mu2  = s2.x * (1.f/384.f);
  float var2 = s2.y * (1.f/384.f) - mu2*mu2;
  float zn = (zi - mu2) * rsqrtf(var2 + 1e-5f) * n1w[c] + n1b[c];
  // roll(-3,-3) then 7x7 window partition
  int ai = i - 3; if (ai < 0) ai += HPc;
  int aj = j - 3; if (aj < 0) aj += WPc;
  int win = (ai/7)*9 + (aj/7);
  int tok = (ai%7)*7 + (aj%7);
  wbuf[(((size_t)b*NWc + win)*NTOKc + tok)*C2c + c] = zn;
}

// ---------------- LN (n2) on cropped tokens: z -> out ----------------
__global__ __launch_bounds__(384)
void ln2_kernel(const float* __restrict__ z, const float* __restrict__ nw,
                const float* __restrict__ nb, float* __restrict__ out)
{
  __shared__ float red[12];
  int tc = blockIdx.x;                // cropped token id
  int c = threadIdx.x;
  float v = z[(size_t)tc*C2c + c];
  float2 ss = block_reduce_384(v, red);
  float mu  = ss.x * (1.f/384.f);
  float var = ss.y * (1.f/384.f) - mu*mu;
  out[(size_t)tc*C2c + c] = (v - mu) * rsqrtf(var + 1e-5f) * nw[c] + nb[c];
}

// ---------------- tiled fp32 GEMM: C[M,N] = A[M,K] @ W[N,K]^T + bias, fused epilogues ----------------
// EPI 0: plain store (qkv, per-batch chunk)
// EPI 1: scatter-add into cropped z (proj: window-reverse + unshift + residual; pad targets skipped)
// EPI 2: exact GELU store (fc1)
// EPI 3: in-place y = val + z  at cropped-token row (fc2); chunk_off maps chunk row -> token
#define BMt 64
#define BNt 64
#define BKt 16

template<int EPI>
__global__ __launch_bounds__(256)
void gemm_kernel(const float* __restrict__ A, const float* __restrict__ W,
                 const float* __restrict__ bias, float* __restrict__ C,
                 int M, int N, int K,
                 float* __restrict__ zbuf, int chunk_off)
{
  __shared__ float As[BKt][BMt+4];
  __shared__ float Bs[BKt][BNt+4];
  int tid = threadIdx.x;
  int m0 = blockIdx.y * BMt, n0 = blockIdx.x * BNt;
  int tx = tid & 15, ty = tid >> 4;
  int tx4 = tx*4, ty4 = ty*4;
  float acc[4][4] = {};

  int lr = tid >> 2;           // 0..63 tile row
  int lk = (tid & 3) * 4;      // 0,4,8,12
  const float* Arow = A + (size_t)(m0 + lr)*K + lk;
  const float* Wrow = W + (size_t)(n0 + lr)*K + lk;
  bool avalid = (m0 + lr) < M;

  for (int k0 = 0; k0 < K; k0 += BKt) {
    float4 av = avalid ? *(const float4*)(Arow + k0) : make_float4(0.f,0.f,0.f,0.f);
    float4 bv = *(const float4*)(Wrow + k0);
    __syncthreads();
    As[lk+0][lr] = av.x; As[lk+1][lr] = av.y; As[lk+2][lr] = av.z; As[lk+3][lr] = av.w;
    Bs[lk+0][lr] = bv.x; Bs[lk+1][lr] = bv.y; Bs[lk+2][lr] = bv.z; Bs[lk+3][lr] = bv.w;
    __syncthreads();
    #pragma unroll
    for (int kk = 0; kk < BKt; ++kk) {
      const float4 a  = *(const float4*)&As[kk][ty4];
      const float4 bq = *(const float4*)&Bs[kk][tx4];
      acc[0][0] += a.x*bq.x; acc[0][1] += a.x*bq.y; acc[0][2] += a.x*bq.z; acc[0][3] += a.x*bq.w;
      acc[1][0] += a.y*bq.x; acc[1][1] += a.y*bq.y; acc[1][2] += a.y*bq.z; acc[1][3] += a.y*bq.w;
      acc[2][0] += a.z*bq.x; acc[2][1] += a.z*bq.y; acc[2][2] += a.z*bq.z; acc[2][3] += a.z*bq.w;
      acc[3][0] += a.w*bq.x; acc[3][1] += a.w*bq.y; acc[3][2] += a.w*bq.z; acc[3][3] += a.w*bq.w;
    }
  }

  float4 b4 = *(const float4*)&bias[n0 + tx4];
  #pragma unroll
  for (int i2 = 0; i2 < 4; ++i2) {
    int m = m0 + ty4 + i2;
    if (m >= M) break;
    float v0 = acc[i2][0] + b4.x;
    float v1 = acc[i2][1] + b4.y;
    float v2 = acc[i2][2] + b4.z;
    float v3 = acc[i2][3] + b4.w;
    if (EPI == 0) {
      float4 o = make_float4(v0, v1, v2, v3);
      *(float4*)&C[(size_t)m*N + n0 + tx4] = o;
    } else if (EPI == 1) {
      // m (global windowed row) -> (b, win, tok) -> rolled coords -> original coords
      int b = m / TPB;
      int rem = m - b*TPB;
      int win = rem / 49, tok = rem - (rem/49)*49;
      int wh = win/9, ww = win - (win/9)*9;
      int th = tok/7, tw = tok - (tok/7)*7;
      int ria = wh*7 + th, rja = ww*7 + tw;
      int oi = ria + 3; if (oi >= HPc) oi -= HPc;
      int oj = rja + 3; if (oj >= WPc) oj -= WPc;
      if (oi < 60 && oj < 60) {
        size_t zi = (((size_t)b*60 + oi)*60 + oj)*C2c + n0 + tx4;
        float4 zv = *(const float4*)&zbuf[zi];
        zv.x += v0; zv.y += v1; zv.z += v2; zv.w += v3;
        *(float4*)&zbuf[zi] = zv;
      }
    } else if (EPI == 2) {
      float4 o;
      o.x = 0.5f*v0*(1.f + erff(v0*0.70710678118654752f));
      o.y = 0.5f*v1*(1.f + erff(v1*0.70710678118654752f));
      o.z = 0.5f*v2*(1.f + erff(v2*0.70710678118654752f));
      o.w = 0.5f*v3*(1.f + erff(v3*0.70710678118654752f));
      *(float4*)&C[(size_t)m*N + n0 + tx4] = o;
    } else { // EPI == 3: y = val + z, stored in-place into z (cropped layout)
      int tc = chunk_off + m;
      size_t zi = (size_t)tc*C2c + n0 + tx4;
      float4 zv = *(const float4*)&zbuf[zi];
      float4 o = make_float4(v0 + zv.x, v1 + zv.y, v2 + zv.z, v3 + zv.w);
      *(float4*)&zbuf[zi] = o;
    }
  }
}

// ---------------- K3: windowed attention, one block per (window, head), per-batch launch ----------------
__global__ __launch_bounds__(256)
void attn_kernel(const float* __restrict__ qkv, const float* __restrict__ rpb,
                 float* __restrict__ out, int bofs)
{
  __shared__ float qs[49*96];
  __shared__ float kv[49*97];
  __shared__ float S[49*50];
  int blk = blockIdx.x;
  int h   = blk & 3;
  int win = blk >> 2;                // 0..80 within this batch
  const float* base = qkv + (size_t)win*49*1152;
  int tid = threadIdx.x;

  for (int t = tid; t < 49*96; t += 256) {
    int r = t / 96, d = t - (t/96)*96;
    qs[t]          = base[r*1152 +        h*96 + d];
    kv[r*97 + d]   = base[r*1152 + 384 +  h*96 + d];
  }
  __syncthreads();

  const float scale = 0.1020620726159657f;   // 96^-0.5
  int wh = win / 9, ww = win - (win/9)*9;
  for (int idx = tid; idx < 49*49; idx += 256) {
    int r = idx / 49, c = idx - (idx/49)*49;
    float s = 0.f;
    #pragma unroll 8
    for (int k = 0; k < 96; ++k) s += qs[r*96 + k] * kv[c*97 + k];
    s *= scale;
    int r1 = r/7, c1 = r - (r/7)*7;
    int r2 = c/7, c2 = c - (c/7)*7;
    s += rpb[((r1 - r2 + 6)*13 + (c1 - c2 + 6))*HEADS + h];
    int hp1 = wh*7 + r1, wp1 = ww*7 + c1;
    int hp2 = wh*7 + r2, wp2 = ww*7 + c2;
    int g1 = (hp1 < 56 ? 0 : (hp1 < 60 ? 1 : 2))*3 + (wp1 < 56 ? 0 : (wp1 < 60 ? 1 : 2));
    int g2 = (hp2 < 56 ? 0 : (hp2 < 60 ? 1 : 2))*3 + (wp2 < 56 ? 0 : (wp2 < 60 ? 1 : 2));
    if (g1 != g2) s -= 100.f;
    S[r*50 + c] = s;
  }
  __syncthreads();

  // overwrite K with V; softmax rows in parallel (disjoint LDS)
  for (int t = tid; t < 49*96; t += 256) {
    int r = t / 96, d = t - (t/96)*96;
    kv[r*97 + d] = base[r*1152 + 768 + h*96 + d];
  }
  if (tid < 49) {
    float mx = -1e30f;
    for (int c = 0; c < 49; ++c) mx = fmaxf(mx, S[tid*50 + c]);
    float sum = 0.f;
    for (int c = 0; c < 49; ++c) { float e = expf(S[tid*50 + c] - mx); S[tid*50 + c] = e; sum += e; }
    float inv = 1.f / sum;
    for (int c = 0; c < 49; ++c) S[tid*50 + c] *= inv;
  }
  __syncthreads();

  for (int o = tid; o < 49*96; o += 256) {
    int r = o / 96, d = o - (o/96)*96;
    float s = 0.f;
    #pragma unroll 7
    for (int c = 0; c < 49; ++c) s += S[r*50 + c] * kv[c*97 + d];
    out[((size_t)(bofs + win)*49 + r)*C2c + h*96 + d] = s;
  }
}

// ---------------- conv weight pre-transpose: wt2[oc][p*384+c] = conv_w[oc][c][p] ----------------
__global__ void convw_transpose(const float* __restrict__ cw, float* __restrict__ wt)
{
  int t = blockIdx.x * blockDim.x + threadIdx.x;
  if (t >= 192*CONVK) return;
  int oc = t / CONVK;
  int k  = t - oc*CONVK;
  int p  = k / 384;
  int c  = k - p*384;
  wt[t] = cw[((size_t)oc*384 + c)*9 + p];
}

// ---------------- conv as im2col-GEMM: M=28800 pixels, N=192 oc, K=3456; + conv_b + x residual ----------------
__global__ __launch_bounds__(256)
void conv_kernel(const float* __restrict__ y, const float* __restrict__ wt,
                 const float* __restrict__ cb, const float* __restrict__ xres,
                 float* __restrict__ outp)
{
  __shared__ float As[BKt][BMt+4];
  __shared__ float Bs[BKt][BNt+4];
  int tid = threadIdx.x;
  int m0 = blockIdx.y * BMt, n0 = blockIdx.x * BNt;
  int tx = tid & 15, ty = tid >> 4;
  int tx4 = tx*4, ty4 = ty*4;
  float acc[4][4] = {};

  int lr = tid >> 2;
  int lk = (tid & 3) * 4;
  int pix = m0 + lr;
  int pb = pix / 3600;
  int prem = pix - pb*3600;
  int oh = prem / 60, ow = prem - (prem/60)*60;
  const float* Wrow = wt + (size_t)(n0 + lr)*CONVK + lk;

  for (int k0 = 0; k0 < CONVK; k0 += BKt) {
    int p   = k0 / 384;
    int cb0 = k0 - p*384;
    int ih = oh + p/3 - 1;
    int iw = ow + (p - (p/3)*3) - 1;
    float4 av = make_float4(0.f,0.f,0.f,0.f);
    if ((unsigned)ih < 60u && (unsigned)iw < 60u)
      av = *(const float4*)&y[(((size_t)pb*60 + ih)*60 + iw)*C2c + cb0 + lk];
    float4 bv = *(const float4*)(Wrow + k0);
    __syncthreads();
    As[lk+0][lr] = av.x; As[lk+1][lr] = av.y; As[lk+2][lr] = av.z; As[lk+3][lr] = av.w;
    Bs[lk+0][lr] = bv.x; Bs[lk+1][lr] = bv.y; Bs[lk+2][lr] = bv.z; Bs[lk+3][lr] = bv.w;
    __syncthreads();
    #pragma unroll
    for (int kk = 0; kk < BKt; ++kk) {
      const float4 a  = *(const float4*)&As[kk][ty4];
      const float4 bq = *(const float4*)&Bs[kk][tx4];
      acc[0][0] += a.x*bq.x; acc[0][1] += a.x*bq.y; acc[0][2] += a.x*bq.z; acc[0][3] += a.x*bq.w;
      acc[1][0] += a.y*bq.x; acc[1][1] += a.y*bq.y; acc[1][2] += a.y*bq.z; acc[1][3] += a.y*bq.w;
      acc[2][0] += a.z*bq.x; acc[2][1] += a.z*bq.y; acc[2][2] += a.z*bq.z; acc[2][3] += a.z*bq.w;
      acc[3][0] += a.w*bq.x; acc[3][1] += a.w*bq.y; acc[3][2] += a.w*bq.z; acc[3][3] += a.w*bq.w;
    }
  }

  #pragma unroll
  for (int i2 = 0; i2 < 4; ++i2) {
    int m = m0 + ty4 + i2;
    if (m >= TOKC) break;
    int b = m / 3600;
    int rem = m - b*3600;
    int yh = rem / 60, yw = rem - (rem/60)*60;
    #pragma unroll
    for (int j2 = 0; j2 < 4; ++j2) {
      int oc = n0 + tx4 + j2;
      size_t oi = (((size_t)b*192 + oc)*60 + yh)*60 + yw;
      outp[oi] = acc[i2][j2] + cb[oc] + xres[oi];
    }
  }
}

// ---------------- host launcher ----------------
extern "C" void kernel_launch(void* const* d_in, const int* in_sizes, int n_in,
                              void* d_out, int out_size, void* d_ws, size_t ws_size,
                              hipStream_t stream)
{
  const float* x      = (const float*)d_in[0];
  const float* g      = (const float*)d_in[1];
  const float* norm_w = (const float*)d_in[2];
  const float* norm_b = (const float*)d_in[3];
  const float* n1_w   = (const float*)d_in[4];
  const float* n1_b   = (const float*)d_in[5];
  const float* qkv_w  = (const float*)d_in[6];
  const float* qkv_b  = (const float*)d_in[7];
  const float* proj_w = (const float*)d_in[8];
  const float* proj_b = (const float*)d_in[9];
  const float* rpb    = (const float*)d_in[10];
  const float* n2_w   = (const float*)d_in[11];
  const float* n2_b   = (const float*)d_in[12];
  const float* fc1_w  = (const float*)d_in[13];
  const float* fc1_b  = (const float*)d_in[14];
  const float* fc2_w  = (const float*)d_in[15];
  const float* fc2_b  = (const float*)d_in[16];
  const float* conv_w = (const float*)d_in[17];
  const float* conv_b = (const float*)d_in[18];
  float* outp = (float*)d_out;

  // workspace layout (floats): total 28,487,808 fl = 113.95 MB
  float* ws   = (float*)d_ws;
  float* z    = ws;                        // 28800*384  = 11,059,200 (cropped residual; becomes y in-place)
  float* wbuf = z    + (size_t)TOKC*C2c;   // 31752*384  = 12,192,768 (windowed zn / attn_out / LN2-out)
  float* qkvb = wbuf + (size_t)TOKP*C2c;   // 3969*1152  =  4,572,288 (per-batch qkv / MLP hidden chunk)
  float* wt2  = qkvb + (size_t)TPB*3*C2c;  // 192*3456   =    663,552

  // conv weight transpose (independent; launch first)
  convw_transpose<<<(192*CONVK + 255)/256, 256, 0, stream>>>(conv_w, wt2);

  // K1: build + LN1 + LN2 + roll + window
  build_ln_kernel<<<TOKP, 384, 0, stream>>>(x, g, norm_w, norm_b, n1_w, n1_b, z, wbuf);

  // per-batch: QKV GEMM [3969,384]@[1152,384]^T then attention (writes back into wbuf rows of this batch)
  for (int b = 0; b < BATCH; ++b) {
    gemm_kernel<0><<<dim3(1152/BNt, (TPB + BMt - 1)/BMt), 256, 0, stream>>>(
        wbuf + (size_t)b*TPB*C2c, qkv_w, qkv_b, qkvb, TPB, 1152, C2c, nullptr, 0);
    attn_kernel<<<NWc*HEADS, 256, 0, stream>>>(qkvb, rpb, wbuf, b*NWc);
  }

  // proj GEMM + fused window-reverse/unshift residual scatter-add into cropped z
  gemm_kernel<1><<<dim3(C2c/BNt, (TOKP + BMt - 1)/BMt), 256, 0, stream>>>(
      wbuf, proj_w, proj_b, nullptr, TOKP, C2c, C2c, z, 0);

  // LN (n2) on cropped tokens -> wbuf
  ln2_kernel<<<TOKC, 384, 0, stream>>>(z, n2_w, n2_b, wbuf);

  // MLP in 10 chunks of 2880 tokens (hidden reuses qkvb); fc2 adds residual and writes y in-place into z
  const int CHUNK = 2880;
  for (int off = 0; off < TOKC; off += CHUNK) {
    gemm_kernel<2><<<dim3(MLPH/BNt, CHUNK/BMt), 256, 0, stream>>>(
        wbuf + (size_t)off*C2c, fc1_w, fc1_b, qkvb, CHUNK, MLPH, C2c, nullptr, 0);
    gemm_kernel<3><<<dim3(C2c/BNt, CHUNK/BMt), 256, 0, stream>>>(
        qkvb, fc2_w, fc2_b, nullptr, CHUNK, C2c, MLPH, z, off);
  }

  // conv 3x3 (im2col-GEMM) on y(=z) + conv_b + x residual -> NCHW output
  conv_kernel<<<dim3(192/BNt, TOKC/BMt), 256, 0, stream>>>(z, wt2, conv_b, x, outp);
}

// Round 3
// 1358.009 us; speedup vs baseline: 2.8542x; 2.8542x over previous
//
#include <hip/hip_runtime.h>
#include <cstddef>
#include <cstdint>

// ---------------- problem constants ----------------
#define HEADS   4
#define C2c     384
#define HPc     63
#define WPc     63
#define NWc     81
#define BATCH   8
#define TOKP    (BATCH*HPc*WPc)   // 31752 windowed rows
#define TOKC    (BATCH*60*60)     // 28800 cropped tokens
#define MLPH    1536
#define TPB     3969              // windowed rows per batch
#define CONVK   3456              // 384*9
#define CONVN   256               // 192 padded to 256

typedef __attribute__((ext_vector_type(8))) short short8;
typedef __attribute__((ext_vector_type(4))) float f32x4;
typedef unsigned short u16;

__device__ __forceinline__ u16 f2bf(float f) {
  unsigned u = __float_as_uint(f);
  u += 0x7fff + ((u >> 16) & 1);           // RNE
  return (u16)(u >> 16);
}
__device__ __forceinline__ float bf2f(u16 b) { return __uint_as_float((unsigned)b << 16); }

// global -> LDS async 16B: dest = wave-uniform base + lane*16; src per-lane
#define GLOAD16(gp, lp) __builtin_amdgcn_global_load_lds( \
    (const __attribute__((address_space(1))) unsigned*)(gp), \
    (__attribute__((address_space(3))) unsigned*)(lp), 16, 0, 0)

// ---------------- block reduce (384 threads, 6 waves) ----------------
__device__ __forceinline__ float2 block_reduce_384(float v, float* red) {
  __syncthreads();
  float s = v, q = v * v;
  #pragma unroll
  for (int o = 32; o > 0; o >>= 1) {
    s += __shfl_down(s, o);
    q += __shfl_down(q, o);
  }
  int w = threadIdx.x >> 6;
  if ((threadIdx.x & 63) == 0) { red[2*w] = s; red[2*w+1] = q; }
  __syncthreads();
  float ts = red[0]+red[2]+red[4]+red[6]+red[8]+red[10];
  float tq = red[1]+red[3]+red[5]+red[7]+red[9]+red[11];
  return make_float2(ts, tq);
}

// ---------------- K1: concat+pad -> LN(norm) -> z fp32 (cropped); LN(n1)+roll+window -> wbuf bf16 ----------------
__global__ __launch_bounds__(384)
void build_ln_kernel(const float* __restrict__ x, const float* __restrict__ g,
                     const float* __restrict__ nw, const float* __restrict__ nb,
                     const float* __restrict__ n1w, const float* __restrict__ n1b,
                     float* __restrict__ z, u16* __restrict__ wbuf)
{
  __shared__ float red[12];
  int t = blockIdx.x;
  int b = t / (HPc*WPc);
  int rem = t - b*(HPc*WPc);
  int i = rem / WPc, j = rem - (rem / WPc)*WPc;
  int c = threadIdx.x;

  float v = 0.f;
  if (i < 60 && j < 60) {
    if (c < 192) v = x[(((size_t)b*192 + c)*60 + i)*60 + j];
    else         v = g[(((size_t)b*192 + (c-192))*60 + i)*60 + j];
  }
  float2 ss = block_reduce_384(v, red);
  float mu  = ss.x * (1.f/384.f);
  float var = ss.y * (1.f/384.f) - mu*mu;
  float zi  = (v - mu) * rsqrtf(var + 1e-5f) * nw[c] + nb[c];
  if (i < 60 && j < 60)
    z[(((size_t)b*60 + i)*60 + j)*C2c + c] = zi;
  float2 s2 = block_reduce_384(zi, red);
  float mu2  = s2.x * (1.f/384.f);
  float var2 = s2.y * (1.f/384.f) - mu2*mu2;
  float zn = (zi - mu2) * rsqrtf(var2 + 1e-5f) * n1w[c] + n1b[c];
  int ai = i - 3; if (ai < 0) ai += HPc;
  int aj = j - 3; if (aj < 0) aj += WPc;
  int win = (ai/7)*9 + (aj/7);
  int tok = (ai%7)*7 + (aj%7);
  wbuf[(((size_t)b*NWc + win)*49 + tok)*C2c + c] = f2bf(zn);
}

// ---------------- LN (n2): z fp32 -> out bf16 ----------------
__global__ __launch_bounds__(384)
void ln2_kernel(const float* __restrict__ z, const float* __restrict__ nw,
                const float* __restrict__ nb, u16* __restrict__ out)
{
  __shared__ float red[12];
  int tc = blockIdx.x;
  int c = threadIdx.x;
  float v = z[(size_t)tc*C2c + c];
  float2 ss = block_reduce_384(v, red);
  float mu  = ss.x * (1.f/384.f);
  float var = ss.y * (1.f/384.f) - mu*mu;
  out[(size_t)tc*C2c + c] = f2bf((v - mu) * rsqrtf(var + 1e-5f) * nw[c] + nb[c]);
}

// ---------------- weight split: fp32 -> (hi, lo) bf16 ----------------
__global__ void split_w(const float* __restrict__ w, u16* __restrict__ hi, u16* __restrict__ lo, int n)
{
  int t = blockIdx.x*blockDim.x + threadIdx.x;
  if (t >= n) return;
  float v = w[t];
  u16 h = f2bf(v);
  hi[t] = h;
  lo[t] = f2bf(v - bf2f(h));
}

// conv weight: transpose OIHW -> [oc][p*384+c], pad oc to 256 with zeros, split hi/lo
__global__ void split_convw(const float* __restrict__ cw, u16* __restrict__ hi, u16* __restrict__ lo)
{
  int t = blockIdx.x*blockDim.x + threadIdx.x;
  if (t >= CONVN*CONVK) return;
  int oc = t / CONVK, k = t - oc*CONVK;
  int p = k / 384, c = k - p*384;
  float v = (oc < 192) ? cw[((size_t)oc*384 + c)*9 + p] : 0.f;
  u16 h = f2bf(v);
  hi[t] = h;
  lo[t] = f2bf(v - bf2f(h));
}

// ---------------- MFMA GEMM: C[M,N] = A[M,K](bf16) @ (Bh+Bl)[N,K]^T + bias ----------------
// 128x128 tile, BK=64, 4 waves (2x2), 4x4 16x16 frags/wave, 2 MFMA per frag (hi+lo weight terms).
// LDS XOR swizzle: phys_slot = log_slot ^ (row&7), 16B slots, 128B rows.
// EPI 0: fp32 store (qkv)    EPI 1: scatter-add into z (proj: window-reverse + unshift + residual)
// EPI 2: GELU -> bf16 (fc1)  EPI 3: +z residual -> bf16 y at row chunk_off+m (fc2)
template<int EPI>
__global__ __launch_bounds__(256)
void mfma_gemm(const u16* __restrict__ A, const u16* __restrict__ Bh, const u16* __restrict__ Bl,
               const float* __restrict__ bias, float* __restrict__ Cf, u16* __restrict__ Cb,
               float* __restrict__ zbuf, int M, int N, int K, int chunk_off)
{
  __shared__ u16 As [128*64];
  __shared__ u16 Bsh[128*64];
  __shared__ u16 Bsl[128*64];
  int tid = threadIdx.x;
  int lane = tid & 63, w = tid >> 6;
  int wr = w >> 1, wc = w & 1;
  int m0 = blockIdx.y * 128, n0 = blockIdx.x * 128;
  int srow = lane >> 3, sslot = (lane & 7) ^ srow;

  f32x4 acc[4][4];
  #pragma unroll
  for (int i = 0; i < 4; ++i)
    #pragma unroll
    for (int j = 0; j < 4; ++j) acc[i][j] = (f32x4){0.f,0.f,0.f,0.f};

  char* AsB = (char*)As; char* BhB = (char*)Bsh; char* BlB = (char*)Bsl;
  int r15 = lane & 15, kq = lane >> 4;

  for (int k0 = 0; k0 < K; k0 += 64) {
    #pragma unroll
    for (int i = 0; i < 4; ++i) {
      int rblk = w*4 + i;
      int ar = m0 + rblk*8 + srow; if (ar >= M) ar = M - 1;   // clamp: results discarded at store
      int br = n0 + rblk*8 + srow;                            // B rows padded to multiple of 128
      GLOAD16(A  + (size_t)ar*K + k0 + sslot*8, AsB + rblk*1024);
      GLOAD16(Bh + (size_t)br*K + k0 + sslot*8, BhB + rblk*1024);
      GLOAD16(Bl + (size_t)br*K + k0 + sslot*8, BlB + rblk*1024);
    }
    __syncthreads();
    #pragma unroll
    for (int ks = 0; ks < 2; ++ks) {
      int slog = ks*4 + kq;
      short8 af[4], bh[4], bl[4];
      #pragma unroll
      for (int mi = 0; mi < 4; ++mi) {
        int row = wr*64 + mi*16 + r15;
        af[mi] = *(const short8*)(AsB + row*128 + ((slog ^ (row&7))<<4));
      }
      #pragma unroll
      for (int ni = 0; ni < 4; ++ni) {
        int row = wc*64 + ni*16 + r15;
        int off = row*128 + ((slog ^ (row&7))<<4);
        bh[ni] = *(const short8*)(BhB + off);
        bl[ni] = *(const short8*)(BlB + off);
      }
      #pragma unroll
      for (int mi = 0; mi < 4; ++mi)
        #pragma unroll
        for (int ni = 0; ni < 4; ++ni) {
          acc[mi][ni] = __builtin_amdgcn_mfma_f32_16x16x32_bf16(af[mi], bh[ni], acc[mi][ni], 0, 0, 0);
          acc[mi][ni] = __builtin_amdgcn_mfma_f32_16x16x32_bf16(af[mi], bl[ni], acc[mi][ni], 0, 0, 0);
        }
    }
    __syncthreads();
  }

  // epilogue: C row = m0 + wr*64 + mi*16 + fq*4 + j ; col = n0 + wc*64 + ni*16 + fr
  int fq = lane >> 4, fr = lane & 15;
  #pragma unroll
  for (int mi = 0; mi < 4; ++mi) {
    #pragma unroll
    for (int j = 0; j < 4; ++j) {
      int m = m0 + wr*64 + mi*16 + fq*4 + j;
      if (m >= M) continue;
      int zrow = 0; bool zok = true;
      if (EPI == 1) {
        int b = m / TPB;
        int rem = m - b*TPB;
        int win = rem / 49, tok = rem - (rem/49)*49;
        int wh = win/9, ww = win - (win/9)*9;
        int th = tok/7, tw = tok - (tok/7)*7;
        int oi = wh*7 + th + 3; if (oi >= HPc) oi -= HPc;
        int oj = ww*7 + tw + 3; if (oj >= WPc) oj -= WPc;
        zok = (oi < 60 && oj < 60);
        zrow = (b*60 + oi)*60 + oj;
      }
      #pragma unroll
      for (int ni = 0; ni < 4; ++ni) {
        int n = n0 + wc*64 + ni*16 + fr;
        float val = acc[mi][ni][j] + bias[n];
        if (EPI == 0) {
          Cf[(size_t)m*N + n] = val;
        } else if (EPI == 1) {
          if (zok) zbuf[(size_t)zrow*C2c + n] += val;
        } else if (EPI == 2) {
          float ge = 0.5f*val*(1.f + erff(val*0.70710678118654752f));
          Cb[(size_t)m*N + n] = f2bf(ge);
        } else { // EPI == 3
          int tc = chunk_off + m;
          Cb[(size_t)tc*C2c + n] = f2bf(val + zbuf[(size_t)tc*C2c + n]);
        }
      }
    }
  }
}

// ---------------- conv as im2col MFMA GEMM: M=28800 pix, N=256(pad 192), K=3456 ----------------
__global__ __launch_bounds__(256)
void mfma_conv(const u16* __restrict__ Y, const u16* __restrict__ Bh, const u16* __restrict__ Bl,
               const float* __restrict__ cb, const float* __restrict__ xres, float* __restrict__ outp)
{
  __shared__ u16 As [128*64];
  __shared__ u16 Bsh[128*64];
  __shared__ u16 Bsl[128*64];
  int tid = threadIdx.x;
  int lane = tid & 63, w = tid >> 6;
  int wr = w >> 1, wc = w & 1;
  int m0 = blockIdx.y * 128, n0 = blockIdx.x * 128;
  int srow = lane >> 3, sslot = (lane & 7) ^ srow;

  f32x4 acc[4][4];
  #pragma unroll
  for (int i = 0; i < 4; ++i)
    #pragma unroll
    for (int j = 0; j < 4; ++j) acc[i][j] = (f32x4){0.f,0.f,0.f,0.f};

  // hoist per-thread A-gather pixel coords (independent of k0)
  int rowA[4], pbA[4], ohA[4], owA[4];
  #pragma unroll
  for (int i = 0; i < 4; ++i) {
    int idx = i*256 + tid;
    rowA[i] = idx >> 3;
    int pix = m0 + rowA[i];
    int pb = pix / 3600;
    int prem = pix - pb*3600;
    pbA[i] = pb; ohA[i] = prem / 60; owA[i] = prem - (prem/60)*60;
  }

  char* AsB = (char*)As; char* BhB = (char*)Bsh; char* BlB = (char*)Bsl;
  int r15 = lane & 15, kq = lane >> 4;

  for (int k0 = 0; k0 < CONVK; k0 += 64) {
    int p  = k0 / 384;                 // constant within a BK tile (384 % 64 == 0)
    int c0 = k0 - p*384;
    int dh = p/3 - 1, dw = (p - (p/3)*3) - 1;
    #pragma unroll
    for (int i = 0; i < 4; ++i) {
      int rblk = w*4 + i;
      int br = n0 + rblk*8 + srow;
      GLOAD16(Bh + (size_t)br*CONVK + k0 + sslot*8, BhB + rblk*1024);
      GLOAD16(Bl + (size_t)br*CONVK + k0 + sslot*8, BlB + rblk*1024);
    }
    #pragma unroll
    for (int i = 0; i < 4; ++i) {
      int idx = i*256 + tid;
      int row = rowA[i], slot = idx & 7;
      int ih = ohA[i] + dh, iw = owA[i] + dw;
      int4 v = {0,0,0,0};
      if ((unsigned)ih < 60u && (unsigned)iw < 60u)
        v = *(const int4*)(Y + (size_t)(pbA[i]*3600 + ih*60 + iw)*C2c + c0 + slot*8);
      *(int4*)(AsB + row*128 + ((slot ^ (row&7))<<4)) = v;
    }
    __syncthreads();
    #pragma unroll
    for (int ks = 0; ks < 2; ++ks) {
      int slog = ks*4 + kq;
      short8 af[4], bh[4], bl[4];
      #pragma unroll
      for (int mi = 0; mi < 4; ++mi) {
        int row = wr*64 + mi*16 + r15;
        af[mi] = *(const short8*)(AsB + row*128 + ((slog ^ (row&7))<<4));
      }
      #pragma unroll
      for (int ni = 0; ni < 4; ++ni) {
        int row = wc*64 + ni*16 + r15;
        int off = row*128 + ((slog ^ (row&7))<<4);
        bh[ni] = *(const short8*)(BhB + off);
        bl[ni] = *(const short8*)(BlB + off);
      }
      #pragma unroll
      for (int mi = 0; mi < 4; ++mi)
        #pragma unroll
        for (int ni = 0; ni < 4; ++ni) {
          acc[mi][ni] = __builtin_amdgcn_mfma_f32_16x16x32_bf16(af[mi], bh[ni], acc[mi][ni], 0, 0, 0);
          acc[mi][ni] = __builtin_amdgcn_mfma_f32_16x16x32_bf16(af[mi], bl[ni], acc[mi][ni], 0, 0, 0);
        }
    }
    __syncthreads();
  }

  int fq = lane >> 4, fr = lane & 15;
  #pragma unroll
  for (int mi = 0; mi < 4; ++mi) {
    #pragma unroll
    for (int j = 0; j < 4; ++j) {
      int m = m0 + wr*64 + mi*16 + fq*4 + j;          // pixel id, always < 28800
      int pb = m / 3600;
      int rem = m - pb*3600;
      int oh = rem / 60, ow = rem - (rem/60)*60;
      #pragma unroll
      for (int ni = 0; ni < 4; ++ni) {
        int oc = n0 + wc*64 + ni*16 + fr;
        if (oc >= 192) continue;
        size_t oi = ((size_t)pb*192 + oc)*3600 + oh*60 + ow;
        outp[oi] = acc[mi][ni][j] + cb[oc] + xres[oi];
      }
    }
  }
}

// ---------------- windowed attention (fp32, per-batch), out -> bf16 wbuf ----------------
__global__ __launch_bounds__(256)
void attn_kernel(const float* __restrict__ qkv, const float* __restrict__ rpb,
                 u16* __restrict__ out, int bofs)
{
  __shared__ float qs[49*96];
  __shared__ float kv[49*97];
  __shared__ float S[49*50];
  int blk = blockIdx.x;
  int h   = blk & 3;
  int win = blk >> 2;
  const float* base = qkv + (size_t)win*49*1152;
  int tid = threadIdx.x;

  for (int t = tid; t < 49*96; t += 256) {
    int r = t / 96, d = t - (t/96)*96;
    qs[t]        = base[r*1152 +       h*96 + d];
    kv[r*97 + d] = base[r*1152 + 384 + h*96 + d];
  }
  __syncthreads();

  const float scale = 0.1020620726159657f;
  int wh = win / 9, ww = win - (win/9)*9;
  for (int idx = tid; idx < 49*49; idx += 256) {
    int r = idx / 49, c = idx - (idx/49)*49;
    float s = 0.f;
    #pragma unroll 8
    for (int k = 0; k < 96; ++k) s += qs[r*96 + k] * kv[c*97 + k];
    s *= scale;
    int r1 = r/7, c1 = r - (r/7)*7;
    int r2 = c/7, c2 = c - (c/7)*7;
    s += rpb[((r1 - r2 + 6)*13 + (c1 - c2 + 6))*HEADS + h];
    int hp1 = wh*7 + r1, wp1 = ww*7 + c1;
    int hp2 = wh*7 + r2, wp2 = ww*7 + c2;
    int g1 = (hp1 < 56 ? 0 : (hp1 < 60 ? 1 : 2))*3 + (wp1 < 56 ? 0 : (wp1 < 60 ? 1 : 2));
    int g2 = (hp2 < 56 ? 0 : (hp2 < 60 ? 1 : 2))*3 + (wp2 < 56 ? 0 : (wp2 < 60 ? 1 : 2));
    if (g1 != g2) s -= 100.f;
    S[r*50 + c] = s;
  }
  __syncthreads();

  for (int t = tid; t < 49*96; t += 256) {
    int r = t / 96, d = t - (t/96)*96;
    kv[r*97 + d] = base[r*1152 + 768 + h*96 + d];
  }
  if (tid < 49) {
    float mx = -1e30f;
    for (int c = 0; c < 49; ++c) mx = fmaxf(mx, S[tid*50 + c]);
    float sum = 0.f;
    for (int c = 0; c < 49; ++c) { float e = expf(S[tid*50 + c] - mx); S[tid*50 + c] = e; sum += e; }
    float inv = 1.f / sum;
    for (int c = 0; c < 49; ++c) S[tid*50 + c] *= inv;
  }
  __syncthreads();

  for (int o = tid; o < 49*96; o += 256) {
    int r = o / 96, d = o - (o/96)*96;
    float s = 0.f;
    #pragma unroll 7
    for (int c = 0; c < 49; ++c) s += S[r*50 + c] * kv[c*97 + d];
    out[((size_t)(bofs + win)*49 + r)*C2c + h*96 + d] = f2bf(s);
  }
}

// ---------------- host launcher ----------------
extern "C" void kernel_launch(void* const* d_in, const int* in_sizes, int n_in,
                              void* d_out, int out_size, void* d_ws, size_t ws_size,
                              hipStream_t stream)
{
  const float* x      = (const float*)d_in[0];
  const float* g      = (const float*)d_in[1];
  const float* norm_w = (const float*)d_in[2];
  const float* norm_b = (const float*)d_in[3];
  const float* n1_w   = (const float*)d_in[4];
  const float* n1_b   = (const float*)d_in[5];
  const float* qkv_w  = (const float*)d_in[6];
  const float* qkv_b  = (const float*)d_in[7];
  const float* proj_w = (const float*)d_in[8];
  const float* proj_b = (const float*)d_in[9];
  const float* rpb    = (const float*)d_in[10];
  const float* n2_w   = (const float*)d_in[11];
  const float* n2_b   = (const float*)d_in[12];
  const float* fc1_w  = (const float*)d_in[13];
  const float* fc1_b  = (const float*)d_in[14];
  const float* fc2_w  = (const float*)d_in[15];
  const float* fc2_b  = (const float*)d_in[16];
  const float* conv_w = (const float*)d_in[17];
  const float* conv_b = (const float*)d_in[18];
  float* outp = (float*)d_out;

  // ---- workspace: 97.5 MB ----
  char* p = (char*)d_ws;
  float* z    = (float*)p;  p += (size_t)TOKC*C2c*4;      // 44.24 MB residual (fp32)
  u16*  wbuf  = (u16*)p;    p += (size_t)TOKP*C2c*2;      // 24.39 MB  zn-window -> attn-out -> ln2-out -> y
  float* qkvb = (float*)p;                                 // 18.29 MB  per-batch qkv fp32
  u16*  hid   = (u16*)qkvb;                                //           / MLP hidden bf16 (17.7 MB)
  p += (size_t)TPB*1152*4;
  u16* qkvwh = (u16*)p; p += 442368*2;
  u16* qkvwl = (u16*)p; p += 442368*2;
  u16* pwh   = (u16*)p; p += 147456*2;
  u16* pwl   = (u16*)p; p += 147456*2;
  u16* f1wh  = (u16*)p; p += 589824*2;
  u16* f1wl  = (u16*)p; p += 589824*2;
  u16* f2wh  = (u16*)p; p += 589824*2;
  u16* f2wl  = (u16*)p; p += 589824*2;
  u16* cvwh  = (u16*)p; p += (size_t)CONVN*CONVK*2;
  u16* cvwl  = (u16*)p; p += (size_t)CONVN*CONVK*2;

  // weight splits (independent)
  split_w<<<(442368+255)/256, 256, 0, stream>>>(qkv_w, qkvwh, qkvwl, 442368);
  split_w<<<(147456+255)/256, 256, 0, stream>>>(proj_w, pwh, pwl, 147456);
  split_w<<<(589824+255)/256, 256, 0, stream>>>(fc1_w, f1wh, f1wl, 589824);
  split_w<<<(589824+255)/256, 256, 0, stream>>>(fc2_w, f2wh, f2wl, 589824);
  split_convw<<<(CONVN*CONVK+255)/256, 256, 0, stream>>>(conv_w, cvwh, cvwl);

  // K1: concat+pad+LN1 -> z ; LN(n1)+roll+window -> wbuf
  build_ln_kernel<<<TOKP, 384, 0, stream>>>(x, g, norm_w, norm_b, n1_w, n1_b, z, wbuf);

  // per-batch: qkv GEMM -> fp32, attention -> bf16 back into wbuf
  for (int b = 0; b < BATCH; ++b) {
    mfma_gemm<0><<<dim3(9, 32), 256, 0, stream>>>(
        wbuf + (size_t)b*TPB*C2c, qkvwh, qkvwl, qkv_b, qkvb, nullptr, nullptr, TPB, 1152, 384, 0);
    attn_kernel<<<NWc*HEADS, 256, 0, stream>>>(qkvb, rpb, wbuf, b*NWc);
  }

  // proj GEMM + window-reverse/unshift scatter-add into z
  mfma_gemm<1><<<dim3(3, 249), 256, 0, stream>>>(
      wbuf, pwh, pwl, proj_b, nullptr, nullptr, z, TOKP, 384, 384, 0);

  // LN (n2): z -> wbuf (rows 0..28799)
  ln2_kernel<<<TOKC, 384, 0, stream>>>(z, n2_w, n2_b, wbuf);

  // MLP in 5 chunks of 5760 tokens; fc2 adds z residual, writes y bf16 into wbuf rows
  const int CHUNK = 5760;
  for (int off = 0; off < TOKC; off += CHUNK) {
    mfma_gemm<2><<<dim3(12, 45), 256, 0, stream>>>(
        wbuf + (size_t)off*C2c, f1wh, f1wl, fc1_b, nullptr, hid, nullptr, CHUNK, MLPH, 384, 0);
    mfma_gemm<3><<<dim3(3, 45), 256, 0, stream>>>(
        hid, f2wh, f2wl, fc2_b, nullptr, wbuf, z, CHUNK, 384, MLPH, off);
  }

  // conv 3x3 im2col MFMA + conv_b + x residual -> NCHW out
  mfma_conv<<<dim3(2, 225), 256, 0, stream>>>(wbuf, cvwh, cvwl, conv_b, x, outp);
}

// Round 5
// 1279.181 us; speedup vs baseline: 3.0301x; 1.0616x over previous
//
#include <hip/hip_runtime.h>
#include <cstddef>
#include <cstdint>

// ---------------- problem constants ----------------
#define HEADS   4
#define C2c     384
#define HPc     63
#define WPc     63
#define NWc     81
#define BATCH   8
#define TOKP    (BATCH*HPc*WPc)   // 31752 windowed rows
#define TOKC    (BATCH*60*60)     // 28800 cropped tokens
#define MLPH    1536
#define TPB     3969              // windowed rows per batch
#define CONVK   3456              // 384*9
#define CONVN   256               // 192 padded to 256

typedef __attribute__((ext_vector_type(8))) short short8;
typedef __attribute__((ext_vector_type(4))) float f32x4;
typedef unsigned short u16;

__device__ __forceinline__ u16 f2bf(float f) {
  unsigned u = __float_as_uint(f);
  u += 0x7fff + ((u >> 16) & 1);           // RNE
  return (u16)(u >> 16);
}
__device__ __forceinline__ float bf2f(u16 b) { return __uint_as_float((unsigned)b << 16); }

// global -> LDS async 16B: dest = wave-uniform base + lane*16; src per-lane
#define GLOAD16(gp, lp) __builtin_amdgcn_global_load_lds( \
    (const __attribute__((address_space(1))) unsigned*)(gp), \
    (__attribute__((address_space(3))) unsigned*)(lp), 16, 0, 0)

// ---------------- block reduce (384 threads, 6 waves) ----------------
__device__ __forceinline__ float2 block_reduce_384(float v, float* red) {
  __syncthreads();
  float s = v, q = v * v;
  #pragma unroll
  for (int o = 32; o > 0; o >>= 1) {
    s += __shfl_down(s, o);
    q += __shfl_down(q, o);
  }
  int w = threadIdx.x >> 6;
  if ((threadIdx.x & 63) == 0) { red[2*w] = s; red[2*w+1] = q; }
  __syncthreads();
  float ts = red[0]+red[2]+red[4]+red[6]+red[8]+red[10];
  float tq = red[1]+red[3]+red[5]+red[7]+red[9]+red[11];
  return make_float2(ts, tq);
}

// ---------------- K1a: concat+pad -> LN(norm) [store mu,rsig]; LN(n1)+roll+window -> wbuf bf16 ----------------
__global__ __launch_bounds__(384)
void k1a_kernel(const float* __restrict__ x, const float* __restrict__ g,
                const float* __restrict__ nw, const float* __restrict__ nb,
                const float* __restrict__ n1w, const float* __restrict__ n1b,
                float* __restrict__ musig, u16* __restrict__ wbuf)
{
  __shared__ float red[12];
  int t = blockIdx.x;
  int b = t / (HPc*WPc);
  int rem = t - b*(HPc*WPc);
  int i = rem / WPc, j = rem - (rem / WPc)*WPc;
  int c = threadIdx.x;

  float v = 0.f;
  if (i < 60 && j < 60) {
    if (c < 192) v = x[(((size_t)b*192 + c)*60 + i)*60 + j];
    else         v = g[(((size_t)b*192 + (c-192))*60 + i)*60 + j];
  }
  float2 ss = block_reduce_384(v, red);
  float mu  = ss.x * (1.f/384.f);
  float var = ss.y * (1.f/384.f) - mu*mu;
  float rs  = rsqrtf(var + 1e-5f);
  if (c == 0) { musig[2*t] = mu; musig[2*t+1] = rs; }
  float zi  = (v - mu) * rs * nw[c] + nb[c];
  float2 s2 = block_reduce_384(zi, red);
  float mu2  = s2.x * (1.f/384.f);
  float var2 = s2.y * (1.f/384.f) - mu2*mu2;
  float zn = (zi - mu2) * rsqrtf(var2 + 1e-5f) * n1w[c] + n1b[c];
  int ai = i - 3; if (ai < 0) ai += HPc;
  int aj = j - 3; if (aj < 0) aj += WPc;
  int win = (ai/7)*9 + (aj/7);
  int tok = (ai%7)*7 + (aj%7);
  wbuf[(((size_t)b*NWc + win)*49 + tok)*C2c + c] = f2bf(zn);
}

// ---------------- K1b: recompute z fp32 (cropped) from x,g and stored mu/rsig ----------------
__global__ __launch_bounds__(384)
void k1b_kernel(const float* __restrict__ x, const float* __restrict__ g,
                const float* __restrict__ nw, const float* __restrict__ nb,
                const float* __restrict__ musig, float* __restrict__ z)
{
  int tc = blockIdx.x;
  int b = tc / 3600;
  int rem = tc - b*3600;
  int i = rem / 60, j = rem - (rem/60)*60;
  int t = b*(HPc*WPc) + i*WPc + j;          // padded token id
  int c = threadIdx.x;
  float v;
  if (c < 192) v = x[(((size_t)b*192 + c)*60 + i)*60 + j];
  else         v = g[(((size_t)b*192 + (c-192))*60 + i)*60 + j];
  float mu = musig[2*t], rs = musig[2*t+1];
  z[(size_t)tc*C2c + c] = (v - mu) * rs * nw[c] + nb[c];
}

// ---------------- LN (n2): z fp32 -> out bf16 ----------------
__global__ __launch_bounds__(384)
void ln2_kernel(const float* __restrict__ z, const float* __restrict__ nw,
                const float* __restrict__ nb, u16* __restrict__ out)
{
  __shared__ float red[12];
  int tc = blockIdx.x;
  int c = threadIdx.x;
  float v = z[(size_t)tc*C2c + c];
  float2 ss = block_reduce_384(v, red);
  float mu  = ss.x * (1.f/384.f);
  float var = ss.y * (1.f/384.f) - mu*mu;
  out[(size_t)tc*C2c + c] = f2bf((v - mu) * rsqrtf(var + 1e-5f) * nw[c] + nb[c]);
}

// ---------------- fp32 -> bf16 bulk convert ----------------
__global__ __launch_bounds__(256)
void f2bf_kernel(const float* __restrict__ in, u16* __restrict__ out, int n4)
{
  int t = blockIdx.x*256 + threadIdx.x;
  if (t >= n4) return;
  float4 v = ((const float4*)in)[t];
  ushort4 o;
  o.x = f2bf(v.x); o.y = f2bf(v.y); o.z = f2bf(v.z); o.w = f2bf(v.w);
  ((ushort4*)out)[t] = o;
}

// ---------------- weight split: fp32 -> (hi, lo) bf16 ----------------
__global__ void split_w(const float* __restrict__ w, u16* __restrict__ hi, u16* __restrict__ lo, int n)
{
  int t = blockIdx.x*blockDim.x + threadIdx.x;
  if (t >= n) return;
  float v = w[t];
  u16 h = f2bf(v);
  hi[t] = h;
  lo[t] = f2bf(v - bf2f(h));
}

// conv weight: transpose OIHW -> [oc][p*384+c], pad oc to 256 with zeros, split hi/lo
__global__ void split_convw(const float* __restrict__ cw, u16* __restrict__ hi, u16* __restrict__ lo)
{
  int t = blockIdx.x*blockDim.x + threadIdx.x;
  if (t >= CONVN*CONVK) return;
  int oc = t / CONVK, k = t - oc*CONVK;
  int p = k / 384, c = k - p*384;
  float v = (oc < 192) ? cw[((size_t)oc*384 + c)*9 + p] : 0.f;
  u16 h = f2bf(v);
  hi[t] = h;
  lo[t] = f2bf(v - bf2f(h));
}

// ---------------- MFMA GEMM: C[M,N] = A[M,K](bf16) @ (Bh+Bl)[rows N, stride ldb]^T + bias ----------------
// 128x128 tile, BK=64, 4 waves (2x2), 4x4 16x16 frags/wave, 2 MFMA per frag (hi+lo weight terms).
// LDS XOR swizzle: phys_slot = log_slot ^ (row&7), 16B slots, 128B rows.  K always multiple of 64; lda == K.
// EPI 0: bf16 store (qkv)   EPI 1: scatter-add into z (proj: window-reverse + unshift + residual)
// EPI 2: GELU -> bf16 (fc1 col-chunk, store stride N)  EPI 3: z[m*384+n] += val (+bias if addbias) (fc2 partial)
template<int EPI>
__global__ __launch_bounds__(256)
void mfma_gemm(const u16* __restrict__ A, const u16* __restrict__ Bh, const u16* __restrict__ Bl,
               const float* __restrict__ bias, u16* __restrict__ Cb, float* __restrict__ zbuf,
               int M, int N, int K, int ldb, int addbias)
{
  __shared__ u16 As [128*64];
  __shared__ u16 Bsh[128*64];
  __shared__ u16 Bsl[128*64];
  int tid = threadIdx.x;
  int lane = tid & 63, w = tid >> 6;
  int wr = w >> 1, wc = w & 1;
  int m0 = blockIdx.y * 128, n0 = blockIdx.x * 128;
  int srow = lane >> 3, sslot = (lane & 7) ^ srow;

  f32x4 acc[4][4];
  #pragma unroll
  for (int i = 0; i < 4; ++i)
    #pragma unroll
    for (int j = 0; j < 4; ++j) acc[i][j] = (f32x4){0.f,0.f,0.f,0.f};

  char* AsB = (char*)As; char* BhB = (char*)Bsh; char* BlB = (char*)Bsl;
  int r15 = lane & 15, kq = lane >> 4;

  for (int k0 = 0; k0 < K; k0 += 64) {
    #pragma unroll
    for (int i = 0; i < 4; ++i) {
      int rblk = w*4 + i;
      int ar = m0 + rblk*8 + srow; if (ar >= M) ar = M - 1;   // clamp: results discarded at store
      int br = n0 + rblk*8 + srow;                            // B row count is exact multiple of 128
      GLOAD16(A  + (size_t)ar*K   + k0 + sslot*8, AsB + rblk*1024);
      GLOAD16(Bh + (size_t)br*ldb + k0 + sslot*8, BhB + rblk*1024);
      GLOAD16(Bl + (size_t)br*ldb + k0 + sslot*8, BlB + rblk*1024);
    }
    __syncthreads();
    #pragma unroll
    for (int ks = 0; ks < 2; ++ks) {
      int slog = ks*4 + kq;
      short8 af[4], bh[4], bl[4];
      #pragma unroll
      for (int mi = 0; mi < 4; ++mi) {
        int row = wr*64 + mi*16 + r15;
        af[mi] = *(const short8*)(AsB + row*128 + ((slog ^ (row&7))<<4));
      }
      #pragma unroll
      for (int ni = 0; ni < 4; ++ni) {
        int row = wc*64 + ni*16 + r15;
        int off = row*128 + ((slog ^ (row&7))<<4);
        bh[ni] = *(const short8*)(BhB + off);
        bl[ni] = *(const short8*)(BlB + off);
      }
      #pragma unroll
      for (int mi = 0; mi < 4; ++mi)
        #pragma unroll
        for (int ni = 0; ni < 4; ++ni) {
          acc[mi][ni] = __builtin_amdgcn_mfma_f32_16x16x32_bf16(af[mi], bh[ni], acc[mi][ni], 0, 0, 0);
          acc[mi][ni] = __builtin_amdgcn_mfma_f32_16x16x32_bf16(af[mi], bl[ni], acc[mi][ni], 0, 0, 0);
        }
    }
    __syncthreads();
  }

  // epilogue: C row = m0 + wr*64 + mi*16 + fq*4 + j ; col = n0 + wc*64 + ni*16 + fr
  int fq = lane >> 4, fr = lane & 15;
  #pragma unroll
  for (int mi = 0; mi < 4; ++mi) {
    #pragma unroll
    for (int j = 0; j < 4; ++j) {
      int m = m0 + wr*64 + mi*16 + fq*4 + j;
      if (m >= M) continue;
      int zrow = 0; bool zok = true;
      if (EPI == 1) {
        int b = m / TPB;
        int rem = m - b*TPB;
        int win = rem / 49, tok = rem - (rem/49)*49;
        int wh = win/9, ww = win - (win/9)*9;
        int th = tok/7, tw = tok - (tok/7)*7;
        int oi = wh*7 + th + 3; if (oi >= HPc) oi -= HPc;
        int oj = ww*7 + tw + 3; if (oj >= WPc) oj -= WPc;
        zok = (oi < 60 && oj < 60);
        zrow = (b*60 + oi)*60 + oj;
      }
      #pragma unroll
      for (int ni = 0; ni < 4; ++ni) {
        int n = n0 + wc*64 + ni*16 + fr;
        float val = acc[mi][ni][j];
        if (EPI == 0) {
          Cb[(size_t)m*N + n] = f2bf(val + bias[n]);
        } else if (EPI == 1) {
          if (zok) zbuf[(size_t)zrow*C2c + n] += val + bias[n];
        } else if (EPI == 2) {
          float vv = val + bias[n];
          float ge = 0.5f*vv*(1.f + erff(vv*0.70710678118654752f));
          Cb[(size_t)m*N + n] = f2bf(ge);
        } else { // EPI == 3
          float vv = val + (addbias ? bias[n] : 0.f);
          zbuf[(size_t)m*C2c + n] += vv;
        }
      }
    }
  }
}

// ---------------- conv as im2col MFMA GEMM: M=28800 pix, N=256(pad 192), K=3456 ----------------
__global__ __launch_bounds__(256)
void mfma_conv(const u16* __restrict__ Y, const u16* __restrict__ Bh, const u16* __restrict__ Bl,
               const float* __restrict__ cb, const float* __restrict__ xres, float* __restrict__ outp)
{
  __shared__ u16 As [128*64];
  __shared__ u16 Bsh[128*64];
  __shared__ u16 Bsl[128*64];
  int tid = threadIdx.x;
  int lane = tid & 63, w = tid >> 6;
  int wr = w >> 1, wc = w & 1;
  int m0 = blockIdx.y * 128, n0 = blockIdx.x * 128;
  int srow = lane >> 3, sslot = (lane & 7) ^ srow;

  f32x4 acc[4][4];
  #pragma unroll
  for (int i = 0; i < 4; ++i)
    #pragma unroll
    for (int j = 0; j < 4; ++j) acc[i][j] = (f32x4){0.f,0.f,0.f,0.f};

  int rowA[4], pbA[4], ohA[4], owA[4];
  #pragma unroll
  for (int i = 0; i < 4; ++i) {
    int idx = i*256 + tid;
    rowA[i] = idx >> 3;
    int pix = m0 + rowA[i];
    int pb = pix / 3600;
    int prem = pix - pb*3600;
    pbA[i] = pb; ohA[i] = prem / 60; owA[i] = prem - (prem/60)*60;
  }

  char* AsB = (char*)As; char* BhB = (char*)Bsh; char* BlB = (char*)Bsl;
  int r15 = lane & 15, kq = lane >> 4;

  for (int k0 = 0; k0 < CONVK; k0 += 64) {
    int p  = k0 / 384;
    int c0 = k0 - p*384;
    int dh = p/3 - 1, dw = (p - (p/3)*3) - 1;
    #pragma unroll
    for (int i = 0; i < 4; ++i) {
      int rblk = w*4 + i;
      int br = n0 + rblk*8 + srow;
      GLOAD16(Bh + (size_t)br*CONVK + k0 + sslot*8, BhB + rblk*1024);
      GLOAD16(Bl + (size_t)br*CONVK + k0 + sslot*8, BlB + rblk*1024);
    }
    #pragma unroll
    for (int i = 0; i < 4; ++i) {
      int idx = i*256 + tid;
      int row = rowA[i], slot = idx & 7;
      int ih = ohA[i] + dh, iw = owA[i] + dw;
      int4 v = {0,0,0,0};
      if ((unsigned)ih < 60u && (unsigned)iw < 60u)
        v = *(const int4*)(Y + (size_t)(pbA[i]*3600 + ih*60 + iw)*C2c + c0 + slot*8);
      *(int4*)(AsB + row*128 + ((slot ^ (row&7))<<4)) = v;
    }
    __syncthreads();
    #pragma unroll
    for (int ks = 0; ks < 2; ++ks) {
      int slog = ks*4 + kq;
      short8 af[4], bh[4], bl[4];
      #pragma unroll
      for (int mi = 0; mi < 4; ++mi) {
        int row = wr*64 + mi*16 + r15;
        af[mi] = *(const short8*)(AsB + row*128 + ((slog ^ (row&7))<<4));
      }
      #pragma unroll
      for (int ni = 0; ni < 4; ++ni) {
        int row = wc*64 + ni*16 + r15;
        int off = row*128 + ((slog ^ (row&7))<<4);
        bh[ni] = *(const short8*)(BhB + off);
        bl[ni] = *(const short8*)(BlB + off);
      }
      #pragma unroll
      for (int mi = 0; mi < 4; ++mi)
        #pragma unroll
        for (int ni = 0; ni < 4; ++ni) {
          acc[mi][ni] = __builtin_amdgcn_mfma_f32_16x16x32_bf16(af[mi], bh[ni], acc[mi][ni], 0, 0, 0);
          acc[mi][ni] = __builtin_amdgcn_mfma_f32_16x16x32_bf16(af[mi], bl[ni], acc[mi][ni], 0, 0, 0);
        }
    }
    __syncthreads();
  }

  int fq = lane >> 4, fr = lane & 15;
  #pragma unroll
  for (int mi = 0; mi < 4; ++mi) {
    #pragma unroll
    for (int j = 0; j < 4; ++j) {
      int m = m0 + wr*64 + mi*16 + fq*4 + j;
      int pb = m / 3600;
      int rem = m - pb*3600;
      int oh = rem / 60, ow = rem - (rem/60)*60;
      #pragma unroll
      for (int ni = 0; ni < 4; ++ni) {
        int oc = n0 + wc*64 + ni*16 + fr;
        if (oc >= 192) continue;
        size_t oi = ((size_t)pb*192 + oc)*3600 + oh*60 + ow;
        outp[oi] = acc[mi][ni][j] + cb[oc] + xres[oi];
      }
    }
  }
}

// ---------------- windowed attention, one launch, one block per (batch-window, head) ----------------
__global__ __launch_bounds__(256)
void attn_kernel(const u16* __restrict__ qkv, const float* __restrict__ rpb,
                 u16* __restrict__ out)
{
  __shared__ float qs[49*96];
  __shared__ float kv[49*97];
  __shared__ float S[49*50];
  int blk = blockIdx.x;
  int h   = blk & 3;
  int bw  = blk >> 2;                 // b*81 + win
  int win = bw % NWc;
  const u16* base = qkv + (size_t)bw*49*1152;
  int tid = threadIdx.x;

  for (int t = tid; t < 49*96; t += 256) {
    int r = t / 96, d = t - (t/96)*96;
    qs[t]        = bf2f(base[r*1152 +       h*96 + d]);
    kv[r*97 + d] = bf2f(base[r*1152 + 384 + h*96 + d]);
  }
  __syncthreads();

  const float scale = 0.1020620726159657f;
  int wh = win / 9, ww = win - (win/9)*9;
  for (int idx = tid; idx < 49*49; idx += 256) {
    int r = idx / 49, c = idx - (idx/49)*49;
    float s = 0.f;
    #pragma unroll 8
    for (int k = 0; k < 96; ++k) s += qs[r*96 + k] * kv[c*97 + k];
    s *= scale;
    int r1 = r/7, c1 = r - (r/7)*7;
    int r2 = c/7, c2 = c - (c/7)*7;
    s += rpb[((r1 - r2 + 6)*13 + (c1 - c2 + 6))*HEADS + h];
    int hp1 = wh*7 + r1, wp1 = ww*7 + c1;
    int hp2 = wh*7 + r2, wp2 = ww*7 + c2;
    int g1 = (hp1 < 56 ? 0 : (hp1 < 60 ? 1 : 2))*3 + (wp1 < 56 ? 0 : (wp1 < 60 ? 1 : 2));
    int g2 = (hp2 < 56 ? 0 : (hp2 < 60 ? 1 : 2))*3 + (wp2 < 56 ? 0 : (wp2 < 60 ? 1 : 2));
    if (g1 != g2) s -= 100.f;
    S[r*50 + c] = s;
  }
  __syncthreads();

  for (int t = tid; t < 49*96; t += 256) {
    int r = t / 96, d = t - (t/96)*96;
    kv[r*97 + d] = bf2f(base[r*1152 + 768 + h*96 + d]);
  }
  if (tid < 49) {
    float mx = -1e30f;
    for (int c = 0; c < 49; ++c) mx = fmaxf(mx, S[tid*50 + c]);
    float sum = 0.f;
    for (int c = 0; c < 49; ++c) { float e = expf(S[tid*50 + c] - mx); S[tid*50 + c] = e; sum += e; }
    float inv = 1.f / sum;
    for (int c = 0; c < 49; ++c) S[tid*50 + c] *= inv;
  }
  __syncthreads();

  for (int o = tid; o < 49*96; o += 256) {
    int r = o / 96, d = o - (o/96)*96;
    float s = 0.f;
    #pragma unroll 7
    for (int c = 0; c < 49; ++c) s += S[r*50 + c] * kv[c*97 + d];
    out[((size_t)bw*49 + r)*C2c + h*96 + d] = f2bf(s);
  }
}

// ---------------- host launcher ----------------
extern "C" void kernel_launch(void* const* d_in, const int* in_sizes, int n_in,
                              void* d_out, int out_size, void* d_ws, size_t ws_size,
                              hipStream_t stream)
{
  const float* x      = (const float*)d_in[0];
  const float* g      = (const float*)d_in[1];
  const float* norm_w = (const float*)d_in[2];
  const float* norm_b = (const float*)d_in[3];
  const float* n1_w   = (const float*)d_in[4];
  const float* n1_b   = (const float*)d_in[5];
  const float* qkv_w  = (const float*)d_in[6];
  const float* qkv_b  = (const float*)d_in[7];
  const float* proj_w = (const float*)d_in[8];
  const float* proj_b = (const float*)d_in[9];
  const float* rpb    = (const float*)d_in[10];
  const float* n2_w   = (const float*)d_in[11];
  const float* n2_b   = (const float*)d_in[12];
  const float* fc1_w  = (const float*)d_in[13];
  const float* fc1_b  = (const float*)d_in[14];
  const float* fc2_w  = (const float*)d_in[15];
  const float* fc2_b  = (const float*)d_in[16];
  const float* conv_w = (const float*)d_in[17];
  const float* conv_b = (const float*)d_in[18];
  float* outp = (float*)d_out;

  // ---- workspace: 108.4 MB ----
  char* p = (char*)d_ws;
  u16* wbuf = (u16*)p;              p += (size_t)TOKP*C2c*2;        // 24.39 MB zn-window -> attn-out -> ln2-out -> y(bf16)
  char* qr  = p;                    p += (size_t)TOKP*1152*2;       // 73.16 MB qkv bf16 (phase 1)
  u16*   qkvb = (u16*)qr;
  float* z    = (float*)qr;                                          // 44.24 MB fp32 residual (phase 2, overlays qkvb)
  u16*   hid  = (u16*)(qr + (size_t)TOKC*C2c*4);                     // 22.12 MB MLP hidden col-chunk (phase 2)
  u16* qkvwh = (u16*)p; p += 442368*2;
  u16* qkvwl = (u16*)p; p += 442368*2;
  u16* pwh   = (u16*)p; p += 147456*2;
  u16* pwl   = (u16*)p; p += 147456*2;
  u16* f1wh  = (u16*)p; p += 589824*2;
  u16* f1wl  = (u16*)p; p += 589824*2;
  u16* f2wh  = (u16*)p; p += 589824*2;
  u16* f2wl  = (u16*)p; p += 589824*2;
  u16* cvwh  = (u16*)p; p += (size_t)CONVN*CONVK*2;
  u16* cvwl  = (u16*)p; p += (size_t)CONVN*CONVK*2;
  float* musig = (float*)p; p += (size_t)TOKP*2*4;

  // weight splits (independent)
  split_w<<<(442368+255)/256, 256, 0, stream>>>(qkv_w, qkvwh, qkvwl, 442368);
  split_w<<<(147456+255)/256, 256, 0, stream>>>(proj_w, pwh, pwl, 147456);
  split_w<<<(589824+255)/256, 256, 0, stream>>>(fc1_w, f1wh, f1wl, 589824);
  split_w<<<(589824+255)/256, 256, 0, stream>>>(fc2_w, f2wh, f2wl, 589824);
  split_convw<<<(CONVN*CONVK+255)/256, 256, 0, stream>>>(conv_w, cvwh, cvwl);

  // K1a: LN1 stats + LN(n1)+roll+window -> wbuf
  k1a_kernel<<<TOKP, 384, 0, stream>>>(x, g, norm_w, norm_b, n1_w, n1_b, musig, wbuf);

  // qkv GEMM, all batches: [31752,384] @ [1152,384]^T -> bf16
  mfma_gemm<0><<<dim3(9, 249), 256, 0, stream>>>(
      wbuf, qkvwh, qkvwl, qkv_b, qkvb, nullptr, TOKP, 1152, 384, 384, 1);

  // attention, all batches: 2592 blocks; writes attn-out back into wbuf
  attn_kernel<<<BATCH*NWc*HEADS, 256, 0, stream>>>(qkvb, rpb, wbuf);

  // K1b: rebuild fp32 residual z (overlays now-dead qkvb)
  k1b_kernel<<<TOKC, 384, 0, stream>>>(x, g, norm_w, norm_b, musig, z);

  // proj GEMM + window-reverse/unshift scatter-add into z
  mfma_gemm<1><<<dim3(3, 249), 256, 0, stream>>>(
      wbuf, pwh, pwl, proj_b, nullptr, z, TOKP, 384, 384, 384, 1);

  // LN (n2): z -> wbuf rows 0..28799 (bf16)
  ln2_kernel<<<TOKC, 384, 0, stream>>>(z, n2_w, n2_b, wbuf);

  // MLP split along hidden dim: 4 col-chunks of 384; fc2 partials accumulate into z (residual inherent)
  for (int h0 = 0; h0 < MLPH; h0 += 384) {
    mfma_gemm<2><<<dim3(3, 225), 256, 0, stream>>>(
        wbuf, f1wh + (size_t)h0*384, f1wl + (size_t)h0*384, fc1_b + h0,
        hid, nullptr, TOKC, 384, 384, 384, 1);
    mfma_gemm<3><<<dim3(3, 225), 256, 0, stream>>>(
        hid, f2wh + h0, f2wl + h0, fc2_b,
        nullptr, z, TOKC, 384, 384, MLPH, h0 == 0 ? 1 : 0);
  }

  // y (=z) fp32 -> bf16 into wbuf for conv A-staging
  f2bf_kernel<<<(TOKC*C2c/4 + 255)/256, 256, 0, stream>>>(z, wbuf, TOKC*C2c/4);

  // conv 3x3 im2col MFMA + conv_b + x residual -> NCHW out
  mfma_conv<<<dim3(2, 225), 256, 0, stream>>>(wbuf, cvwh, cvwl, conv_b, x, outp);
}

// Round 6
// 1106.940 us; speedup vs baseline: 3.5016x; 1.1556x over previous
//
#include <hip/hip_runtime.h>
#include <cstddef>
#include <cstdint>

// ---------------- problem constants ----------------
#define HEADS   4
#define C2c     384
#define HPc     63
#define WPc     63
#define NWc     81
#define BATCH   8
#define TOKP    (BATCH*HPc*WPc)   // 31752 windowed rows
#define TOKC    (BATCH*60*60)     // 28800 cropped tokens
#define MLPH    1536
#define TPB     3969              // windowed rows per batch
#define CONVK   3456              // 384*9
#define CONVN   256               // 192 padded to 256

typedef __attribute__((ext_vector_type(8))) short short8;
typedef __attribute__((ext_vector_type(4))) float f32x4;
typedef unsigned short u16;

__device__ __forceinline__ u16 f2bf(float f) {
  unsigned u = __float_as_uint(f);
  u += 0x7fff + ((u >> 16) & 1);           // RNE
  return (u16)(u >> 16);
}
__device__ __forceinline__ float bf2f(u16 b) { return __uint_as_float((unsigned)b << 16); }

// global -> LDS async 16B: dest = wave-uniform base + lane*16; src per-lane
#define GLOAD16(gp, lp) __builtin_amdgcn_global_load_lds( \
    (const __attribute__((address_space(1))) unsigned*)(gp), \
    (__attribute__((address_space(3))) unsigned*)(lp), 16, 0, 0)

// ---------------- block reduce (384 threads, 6 waves) ----------------
__device__ __forceinline__ float2 block_reduce_384(float v, float* red) {
  __syncthreads();
  float s = v, q = v * v;
  #pragma unroll
  for (int o = 32; o > 0; o >>= 1) {
    s += __shfl_down(s, o);
    q += __shfl_down(q, o);
  }
  int w = threadIdx.x >> 6;
  if ((threadIdx.x & 63) == 0) { red[2*w] = s; red[2*w+1] = q; }
  __syncthreads();
  float ts = red[0]+red[2]+red[4]+red[6]+red[8]+red[10];
  float tq = red[1]+red[3]+red[5]+red[7]+red[9]+red[11];
  return make_float2(ts, tq);
}

// ---------------- K1a: concat+pad -> LN(norm) [store mu,rsig]; LN(n1)+roll+window -> wbuf bf16 ----------------
__global__ __launch_bounds__(384)
void k1a_kernel(const float* __restrict__ x, const float* __restrict__ g,
                const float* __restrict__ nw, const float* __restrict__ nb,
                const float* __restrict__ n1w, const float* __restrict__ n1b,
                float* __restrict__ musig, u16* __restrict__ wbuf)
{
  __shared__ float red[12];
  int t = blockIdx.x;
  int b = t / (HPc*WPc);
  int rem = t - b*(HPc*WPc);
  int i = rem / WPc, j = rem - (rem / WPc)*WPc;
  int c = threadIdx.x;

  float v = 0.f;
  if (i < 60 && j < 60) {
    if (c < 192) v = x[(((size_t)b*192 + c)*60 + i)*60 + j];
    else         v = g[(((size_t)b*192 + (c-192))*60 + i)*60 + j];
  }
  float2 ss = block_reduce_384(v, red);
  float mu  = ss.x * (1.f/384.f);
  float var = ss.y * (1.f/384.f) - mu*mu;
  float rs  = rsqrtf(var + 1e-5f);
  if (c == 0) { musig[2*t] = mu; musig[2*t+1] = rs; }
  float zi  = (v - mu) * rs * nw[c] + nb[c];
  float2 s2 = block_reduce_384(zi, red);
  float mu2  = s2.x * (1.f/384.f);
  float var2 = s2.y * (1.f/384.f) - mu2*mu2;
  float zn = (zi - mu2) * rsqrtf(var2 + 1e-5f) * n1w[c] + n1b[c];
  int ai = i - 3; if (ai < 0) ai += HPc;
  int aj = j - 3; if (aj < 0) aj += WPc;
  int win = (ai/7)*9 + (aj/7);
  int tok = (ai%7)*7 + (aj%7);
  wbuf[(((size_t)b*NWc + win)*49 + tok)*C2c + c] = f2bf(zn);
}

// ---------------- K1b: recompute z fp32 (cropped) from x,g and stored mu/rsig ----------------
__global__ __launch_bounds__(384)
void k1b_kernel(const float* __restrict__ x, const float* __restrict__ g,
                const float* __restrict__ nw, const float* __restrict__ nb,
                const float* __restrict__ musig, float* __restrict__ z)
{
  int tc = blockIdx.x;
  int b = tc / 3600;
  int rem = tc - b*3600;
  int i = rem / 60, j = rem - (rem/60)*60;
  int t = b*(HPc*WPc) + i*WPc + j;          // padded token id
  int c = threadIdx.x;
  float v;
  if (c < 192) v = x[(((size_t)b*192 + c)*60 + i)*60 + j];
  else         v = g[(((size_t)b*192 + (c-192))*60 + i)*60 + j];
  float mu = musig[2*t], rs = musig[2*t+1];
  z[(size_t)tc*C2c + c] = (v - mu) * rs * nw[c] + nb[c];
}

// ---------------- LN (n2): z fp32 -> out bf16 ----------------
__global__ __launch_bounds__(384)
void ln2_kernel(const float* __restrict__ z, const float* __restrict__ nw,
                const float* __restrict__ nb, u16* __restrict__ out)
{
  __shared__ float red[12];
  int tc = blockIdx.x;
  int c = threadIdx.x;
  float v = z[(size_t)tc*C2c + c];
  float2 ss = block_reduce_384(v, red);
  float mu  = ss.x * (1.f/384.f);
  float var = ss.y * (1.f/384.f) - mu*mu;
  out[(size_t)tc*C2c + c] = f2bf((v - mu) * rsqrtf(var + 1e-5f) * nw[c] + nb[c]);
}

// ---------------- fp32 -> bf16 bulk convert ----------------
__global__ __launch_bounds__(256)
void f2bf_kernel(const float* __restrict__ in, u16* __restrict__ out, int n4)
{
  int t = blockIdx.x*256 + threadIdx.x;
  if (t >= n4) return;
  float4 v = ((const float4*)in)[t];
  ushort4 o;
  o.x = f2bf(v.x); o.y = f2bf(v.y); o.z = f2bf(v.z); o.w = f2bf(v.w);
  ((ushort4*)out)[t] = o;
}

// ---------------- weight split: fp32 -> (hi, lo) bf16 ----------------
__global__ void split_w(const float* __restrict__ w, u16* __restrict__ hi, u16* __restrict__ lo, int n)
{
  int t = blockIdx.x*blockDim.x + threadIdx.x;
  if (t >= n) return;
  float v = w[t];
  u16 h = f2bf(v);
  hi[t] = h;
  lo[t] = f2bf(v - bf2f(h));
}

// conv weight: transpose OIHW -> [oc][p*384+c], pad oc to 256 with zeros, split hi/lo
__global__ void split_convw(const float* __restrict__ cw, u16* __restrict__ hi, u16* __restrict__ lo)
{
  int t = blockIdx.x*blockDim.x + threadIdx.x;
  if (t >= CONVN*CONVK) return;
  int oc = t / CONVK, k = t - oc*CONVK;
  int p = k / 384, c = k - p*384;
  float v = (oc < 192) ? cw[((size_t)oc*384 + c)*9 + p] : 0.f;
  u16 h = f2bf(v);
  hi[t] = h;
  lo[t] = f2bf(v - bf2f(h));
}

// ---------------- MFMA GEMM: C[M,N] = A[M,K](bf16) @ (Bh+Bl)[rows N, stride ldb]^T + bias ----------------
// 128x128 tile, BK=64, 4 waves (2x2), 4x4 16x16 frags/wave, 2 MFMA per frag (hi+lo weight terms).
// LDS XOR swizzle: phys_slot = log_slot ^ (row&7), 16B slots, 128B rows.  K always multiple of 64; lda == K.
// EPI 0: bf16 store (qkv)   EPI 1: scatter-add into z (proj: window-reverse + unshift + residual)
// EPI 2: GELU -> bf16 (fc1 col-chunk, store stride N)  EPI 3: z[m*384+n] += val (+bias if addbias) (fc2 partial)
template<int EPI>
__global__ __launch_bounds__(256)
void mfma_gemm(const u16* __restrict__ A, const u16* __restrict__ Bh, const u16* __restrict__ Bl,
               const float* __restrict__ bias, u16* __restrict__ Cb, float* __restrict__ zbuf,
               int M, int N, int K, int ldb, int addbias)
{
  __shared__ u16 As [128*64];
  __shared__ u16 Bsh[128*64];
  __shared__ u16 Bsl[128*64];
  int tid = threadIdx.x;
  int lane = tid & 63, w = tid >> 6;
  int wr = w >> 1, wc = w & 1;
  int m0 = blockIdx.y * 128, n0 = blockIdx.x * 128;
  int srow = lane >> 3, sslot = (lane & 7) ^ srow;

  f32x4 acc[4][4];
  #pragma unroll
  for (int i = 0; i < 4; ++i)
    #pragma unroll
    for (int j = 0; j < 4; ++j) acc[i][j] = (f32x4){0.f,0.f,0.f,0.f};

  char* AsB = (char*)As; char* BhB = (char*)Bsh; char* BlB = (char*)Bsl;
  int r15 = lane & 15, kq = lane >> 4;

  for (int k0 = 0; k0 < K; k0 += 64) {
    #pragma unroll
    for (int i = 0; i < 4; ++i) {
      int rblk = w*4 + i;
      int ar = m0 + rblk*8 + srow; if (ar >= M) ar = M - 1;   // clamp: results discarded at store
      int br = n0 + rblk*8 + srow;                            // B row count is exact multiple of 128
      GLOAD16(A  + (size_t)ar*K   + k0 + sslot*8, AsB + rblk*1024);
      GLOAD16(Bh + (size_t)br*ldb + k0 + sslot*8, BhB + rblk*1024);
      GLOAD16(Bl + (size_t)br*ldb + k0 + sslot*8, BlB + rblk*1024);
    }
    __syncthreads();
    #pragma unroll
    for (int ks = 0; ks < 2; ++ks) {
      int slog = ks*4 + kq;
      short8 af[4], bh[4], bl[4];
      #pragma unroll
      for (int mi = 0; mi < 4; ++mi) {
        int row = wr*64 + mi*16 + r15;
        af[mi] = *(const short8*)(AsB + row*128 + ((slog ^ (row&7))<<4));
      }
      #pragma unroll
      for (int ni = 0; ni < 4; ++ni) {
        int row = wc*64 + ni*16 + r15;
        int off = row*128 + ((slog ^ (row&7))<<4);
        bh[ni] = *(const short8*)(BhB + off);
        bl[ni] = *(const short8*)(BlB + off);
      }
      #pragma unroll
      for (int mi = 0; mi < 4; ++mi)
        #pragma unroll
        for (int ni = 0; ni < 4; ++ni) {
          acc[mi][ni] = __builtin_amdgcn_mfma_f32_16x16x32_bf16(af[mi], bh[ni], acc[mi][ni], 0, 0, 0);
          acc[mi][ni] = __builtin_amdgcn_mfma_f32_16x16x32_bf16(af[mi], bl[ni], acc[mi][ni], 0, 0, 0);
        }
    }
    __syncthreads();
  }

  // epilogue: C row = m0 + wr*64 + mi*16 + fq*4 + j ; col = n0 + wc*64 + ni*16 + fr
  int fq = lane >> 4, fr = lane & 15;
  #pragma unroll
  for (int mi = 0; mi < 4; ++mi) {
    #pragma unroll
    for (int j = 0; j < 4; ++j) {
      int m = m0 + wr*64 + mi*16 + fq*4 + j;
      if (m >= M) continue;
      int zrow = 0; bool zok = true;
      if (EPI == 1) {
        int b = m / TPB;
        int rem = m - b*TPB;
        int win = rem / 49, tok = rem - (rem/49)*49;
        int wh = win/9, ww = win - (win/9)*9;
        int th = tok/7, tw = tok - (tok/7)*7;
        int oi = wh*7 + th + 3; if (oi >= HPc) oi -= HPc;
        int oj = ww*7 + tw + 3; if (oj >= WPc) oj -= WPc;
        zok = (oi < 60 && oj < 60);
        zrow = (b*60 + oi)*60 + oj;
      }
      #pragma unroll
      for (int ni = 0; ni < 4; ++ni) {
        int n = n0 + wc*64 + ni*16 + fr;
        float val = acc[mi][ni][j];
        if (EPI == 0) {
          Cb[(size_t)m*N + n] = f2bf(val + bias[n]);
        } else if (EPI == 1) {
          if (zok) zbuf[(size_t)zrow*C2c + n] += val + bias[n];
        } else if (EPI == 2) {
          float vv = val + bias[n];
          float ge = 0.5f*vv*(1.f + erff(vv*0.70710678118654752f));
          Cb[(size_t)m*N + n] = f2bf(ge);
        } else { // EPI == 3
          float vv = val + (addbias ? bias[n] : 0.f);
          zbuf[(size_t)m*C2c + n] += vv;
        }
      }
    }
  }
}

// ---------------- conv as im2col MFMA GEMM: M=28800 pix, N=256(pad 192), K=3456 ----------------
__global__ __launch_bounds__(256)
void mfma_conv(const u16* __restrict__ Y, const u16* __restrict__ Bh, const u16* __restrict__ Bl,
               const float* __restrict__ cb, const float* __restrict__ xres, float* __restrict__ outp)
{
  __shared__ u16 As [128*64];
  __shared__ u16 Bsh[128*64];
  __shared__ u16 Bsl[128*64];
  int tid = threadIdx.x;
  int lane = tid & 63, w = tid >> 6;
  int wr = w >> 1, wc = w & 1;
  int m0 = blockIdx.y * 128, n0 = blockIdx.x * 128;
  int srow = lane >> 3, sslot = (lane & 7) ^ srow;

  f32x4 acc[4][4];
  #pragma unroll
  for (int i = 0; i < 4; ++i)
    #pragma unroll
    for (int j = 0; j < 4; ++j) acc[i][j] = (f32x4){0.f,0.f,0.f,0.f};

  int rowA[4], pbA[4], ohA[4], owA[4];
  #pragma unroll
  for (int i = 0; i < 4; ++i) {
    int idx = i*256 + tid;
    rowA[i] = idx >> 3;
    int pix = m0 + rowA[i];
    int pb = pix / 3600;
    int prem = pix - pb*3600;
    pbA[i] = pb; ohA[i] = prem / 60; owA[i] = prem - (prem/60)*60;
  }

  char* AsB = (char*)As; char* BhB = (char*)Bsh; char* BlB = (char*)Bsl;
  int r15 = lane & 15, kq = lane >> 4;

  for (int k0 = 0; k0 < CONVK; k0 += 64) {
    int p  = k0 / 384;
    int c0 = k0 - p*384;
    int dh = p/3 - 1, dw = (p - (p/3)*3) - 1;
    #pragma unroll
    for (int i = 0; i < 4; ++i) {
      int rblk = w*4 + i;
      int br = n0 + rblk*8 + srow;
      GLOAD16(Bh + (size_t)br*CONVK + k0 + sslot*8, BhB + rblk*1024);
      GLOAD16(Bl + (size_t)br*CONVK + k0 + sslot*8, BlB + rblk*1024);
    }
    #pragma unroll
    for (int i = 0; i < 4; ++i) {
      int idx = i*256 + tid;
      int row = rowA[i], slot = idx & 7;
      int ih = ohA[i] + dh, iw = owA[i] + dw;
      int4 v = {0,0,0,0};
      if ((unsigned)ih < 60u && (unsigned)iw < 60u)
        v = *(const int4*)(Y + (size_t)(pbA[i]*3600 + ih*60 + iw)*C2c + c0 + slot*8);
      *(int4*)(AsB + row*128 + ((slot ^ (row&7))<<4)) = v;
    }
    __syncthreads();
    #pragma unroll
    for (int ks = 0; ks < 2; ++ks) {
      int slog = ks*4 + kq;
      short8 af[4], bh[4], bl[4];
      #pragma unroll
      for (int mi = 0; mi < 4; ++mi) {
        int row = wr*64 + mi*16 + r15;
        af[mi] = *(const short8*)(AsB + row*128 + ((slog ^ (row&7))<<4));
      }
      #pragma unroll
      for (int ni = 0; ni < 4; ++ni) {
        int row = wc*64 + ni*16 + r15;
        int off = row*128 + ((slog ^ (row&7))<<4);
        bh[ni] = *(const short8*)(BhB + off);
        bl[ni] = *(const short8*)(BlB + off);
      }
      #pragma unroll
      for (int mi = 0; mi < 4; ++mi)
        #pragma unroll
        for (int ni = 0; ni < 4; ++ni) {
          acc[mi][ni] = __builtin_amdgcn_mfma_f32_16x16x32_bf16(af[mi], bh[ni], acc[mi][ni], 0, 0, 0);
          acc[mi][ni] = __builtin_amdgcn_mfma_f32_16x16x32_bf16(af[mi], bl[ni], acc[mi][ni], 0, 0, 0);
        }
    }
    __syncthreads();
  }

  int fq = lane >> 4, fr = lane & 15;
  #pragma unroll
  for (int mi = 0; mi < 4; ++mi) {
    #pragma unroll
    for (int j = 0; j < 4; ++j) {
      int m = m0 + wr*64 + mi*16 + fq*4 + j;
      int pb = m / 3600;
      int rem = m - pb*3600;
      int oh = rem / 60, ow = rem - (rem/60)*60;
      #pragma unroll
      for (int ni = 0; ni < 4; ++ni) {
        int oc = n0 + wc*64 + ni*16 + fr;
        if (oc >= 192) continue;
        size_t oi = ((size_t)pb*192 + oc)*3600 + oh*60 + ow;
        outp[oi] = acc[mi][ni][j] + cb[oc] + xres[oi];
      }
    }
  }
}

// ---------------- windowed attention, register-tiled; one block per (batch-window, head) ----------------
#define QS_STRIDE 100
#define VS_STRIDE 104
#define SS_STRIDE 53

__global__ __launch_bounds__(256)
void attn_kernel(const u16* __restrict__ qkv, const float* __restrict__ rpb,
                 u16* __restrict__ out)
{
  __shared__ float qs[52*QS_STRIDE];
  __shared__ float ks[52*QS_STRIDE];   // K during QK^T, then V (stride 104)
  __shared__ float S[52*SS_STRIDE];
  int blk = blockIdx.x;
  int h   = blk & 3;
  int bw  = blk >> 2;                 // b*81 + win
  int win = bw % NWc;
  const u16* base = qkv + (size_t)bw*49*1152;
  int tid = threadIdx.x;

  // load Q,K (short8-vectorized)
  for (int t2 = tid; t2 < 588; t2 += 256) {            // 49 rows * 12 groups of 8
    int r = t2 / 12, dq = t2 - (t2/12)*12;
    short8 qv = *(const short8*)(base + r*1152 +       h*96 + dq*8);
    short8 kv = *(const short8*)(base + r*1152 + 384 + h*96 + dq*8);
    #pragma unroll
    for (int e = 0; e < 8; ++e) {
      qs[r*QS_STRIDE + dq*8 + e] = bf2f((u16)qv[e]);
      ks[r*QS_STRIDE + dq*8 + e] = bf2f((u16)kv[e]);
    }
  }
  __syncthreads();

  const float scale = 0.1020620726159657f;   // 96^-0.5
  int wh = win / 9, ww = win - (win/9)*9;

  // QK^T: 13x13 threads, 4x4 outputs each, k blocked by 4 (float4 LDS reads)
  if (tid < 169) {
    int tr = tid / 13, tc = tid - (tid/13)*13;
    int r0 = tr*4, c0 = tc*4;
    float a[4][4] = {};
    for (int k0 = 0; k0 < 96; k0 += 4) {
      float4 qv[4], kv4[4];
      #pragma unroll
      for (int i = 0; i < 4; ++i) qv[i]  = *(const float4*)&qs[(r0+i)*QS_STRIDE + k0];
      #pragma unroll
      for (int j = 0; j < 4; ++j) kv4[j] = *(const float4*)&ks[(c0+j)*QS_STRIDE + k0];
      #pragma unroll
      for (int i = 0; i < 4; ++i)
        #pragma unroll
        for (int j = 0; j < 4; ++j)
          a[i][j] += qv[i].x*kv4[j].x + qv[i].y*kv4[j].y + qv[i].z*kv4[j].z + qv[i].w*kv4[j].w;
    }
    #pragma unroll
    for (int i = 0; i < 4; ++i) {
      int r = r0 + i;
      if (r < 49) {
        int r1 = r/7, c1 = r - (r/7)*7;
        int hp1 = wh*7 + r1, wp1 = ww*7 + c1;
        int g1 = (hp1 < 56 ? 0 : (hp1 < 60 ? 1 : 2))*3 + (wp1 < 56 ? 0 : (wp1 < 60 ? 1 : 2));
        #pragma unroll
        for (int j = 0; j < 4; ++j) {
          int c = c0 + j;
          if (c < 49) {
            int r2 = c/7, c2 = c - (c/7)*7;
            float s = a[i][j]*scale + rpb[((r1 - r2 + 6)*13 + (c1 - c2 + 6))*HEADS + h];
            int hp2 = wh*7 + r2, wp2 = ww*7 + c2;
            int g2 = (hp2 < 56 ? 0 : (hp2 < 60 ? 1 : 2))*3 + (wp2 < 56 ? 0 : (wp2 < 60 ? 1 : 2));
            if (g1 != g2) s -= 100.f;
            S[r*SS_STRIDE + c] = s;
          }
        }
      }
    }
  }
  __syncthreads();

  // V load (into ks, stride 104) overlapped with softmax (tid<49, disjoint rows of S)
  for (int t2 = tid; t2 < 588; t2 += 256) {
    int r = t2 / 12, dq = t2 - (t2/12)*12;
    short8 vv = *(const short8*)(base + r*1152 + 768 + h*96 + dq*8);
    #pragma unroll
    for (int e = 0; e < 8; ++e) ks[r*VS_STRIDE + dq*8 + e] = bf2f((u16)vv[e]);
  }
  if (tid < 49) {
    float mx = -1e30f;
    for (int c = 0; c < 49; ++c) mx = fmaxf(mx, S[tid*SS_STRIDE + c]);
    float sum = 0.f;
    for (int c = 0; c < 49; ++c) { float e = expf(S[tid*SS_STRIDE + c] - mx); S[tid*SS_STRIDE + c] = e; sum += e; }
    float inv = 1.f / sum;
    for (int c = 0; c < 49; ++c) S[tid*SS_STRIDE + c] *= inv;
  }
  __syncthreads();

  // PV: 13x12 threads, 4 rows x 8 cols each (float4 V reads)
  if (tid < 156) {
    int tr2 = tid / 12, tc2 = tid - (tid/12)*12;
    int r0 = tr2*4, d0 = tc2*8;
    float o[4][8] = {};
    for (int c = 0; c < 49; ++c) {
      float4 v0 = *(const float4*)&ks[c*VS_STRIDE + d0];
      float4 v1 = *(const float4*)&ks[c*VS_STRIDE + d0 + 4];
      #pragma unroll
      for (int i = 0; i < 4; ++i) {
        float sv = S[(r0+i)*SS_STRIDE + c];
        o[i][0] += sv*v0.x; o[i][1] += sv*v0.y; o[i][2] += sv*v0.z; o[i][3] += sv*v0.w;
        o[i][4] += sv*v1.x; o[i][5] += sv*v1.y; o[i][6] += sv*v1.z; o[i][7] += sv*v1.w;
      }
    }
    #pragma unroll
    for (int i = 0; i < 4; ++i) {
      int r = r0 + i;
      if (r >= 49) continue;
      ushort4 w0, w1;
      w0.x = f2bf(o[i][0]); w0.y = f2bf(o[i][1]); w0.z = f2bf(o[i][2]); w0.w = f2bf(o[i][3]);
      w1.x = f2bf(o[i][4]); w1.y = f2bf(o[i][5]); w1.z = f2bf(o[i][6]); w1.w = f2bf(o[i][7]);
      size_t ob = ((size_t)bw*49 + r)*C2c + h*96 + d0;
      *(ushort4*)&out[ob]     = w0;
      *(ushort4*)&out[ob + 4] = w1;
    }
  }
}

// ---------------- host launcher ----------------
extern "C" void kernel_launch(void* const* d_in, const int* in_sizes, int n_in,
                              void* d_out, int out_size, void* d_ws, size_t ws_size,
                              hipStream_t stream)
{
  const float* x      = (const float*)d_in[0];
  const float* g      = (const float*)d_in[1];
  const float* norm_w = (const float*)d_in[2];
  const float* norm_b = (const float*)d_in[3];
  const float* n1_w   = (const float*)d_in[4];
  const float* n1_b   = (const float*)d_in[5];
  const float* qkv_w  = (const float*)d_in[6];
  const float* qkv_b  = (const float*)d_in[7];
  const float* proj_w = (const float*)d_in[8];
  const float* proj_b = (const float*)d_in[9];
  const float* rpb    = (const float*)d_in[10];
  const float* n2_w   = (const float*)d_in[11];
  const float* n2_b   = (const float*)d_in[12];
  const float* fc1_w  = (const float*)d_in[13];
  const float* fc1_b  = (const float*)d_in[14];
  const float* fc2_w  = (const float*)d_in[15];
  const float* fc2_b  = (const float*)d_in[16];
  const float* conv_w = (const float*)d_in[17];
  const float* conv_b = (const float*)d_in[18];
  float* outp = (float*)d_out;

  // ---- workspace: 108.4 MB ----
  char* p = (char*)d_ws;
  u16* wbuf = (u16*)p;              p += (size_t)TOKP*C2c*2;        // 24.39 MB zn-window -> attn-out -> ln2-out -> y(bf16)
  char* qr  = p;                    p += (size_t)TOKP*1152*2;       // 73.16 MB qkv bf16 (phase 1)
  u16*   qkvb = (u16*)qr;
  float* z    = (float*)qr;                                          // 44.24 MB fp32 residual (phase 2, overlays qkvb)
  u16*   hid  = (u16*)(qr + (size_t)TOKC*C2c*4);                     // 22.12 MB MLP hidden col-chunk (phase 2)
  u16* qkvwh = (u16*)p; p += 442368*2;
  u16* qkvwl = (u16*)p; p += 442368*2;
  u16* pwh   = (u16*)p; p += 147456*2;
  u16* pwl   = (u16*)p; p += 147456*2;
  u16* f1wh  = (u16*)p; p += 589824*2;
  u16* f1wl  = (u16*)p; p += 589824*2;
  u16* f2wh  = (u16*)p; p += 589824*2;
  u16* f2wl  = (u16*)p; p += 589824*2;
  u16* cvwh  = (u16*)p; p += (size_t)CONVN*CONVK*2;
  u16* cvwl  = (u16*)p; p += (size_t)CONVN*CONVK*2;
  float* musig = (float*)p; p += (size_t)TOKP*2*4;

  // weight splits (independent)
  split_w<<<(442368+255)/256, 256, 0, stream>>>(qkv_w, qkvwh, qkvwl, 442368);
  split_w<<<(147456+255)/256, 256, 0, stream>>>(proj_w, pwh, pwl, 147456);
  split_w<<<(589824+255)/256, 256, 0, stream>>>(fc1_w, f1wh, f1wl, 589824);
  split_w<<<(589824+255)/256, 256, 0, stream>>>(fc2_w, f2wh, f2wl, 589824);
  split_convw<<<(CONVN*CONVK+255)/256, 256, 0, stream>>>(conv_w, cvwh, cvwl);

  // K1a: LN1 stats + LN(n1)+roll+window -> wbuf
  k1a_kernel<<<TOKP, 384, 0, stream>>>(x, g, norm_w, norm_b, n1_w, n1_b, musig, wbuf);

  // qkv GEMM, all batches: [31752,384] @ [1152,384]^T -> bf16
  mfma_gemm<0><<<dim3(9, 249), 256, 0, stream>>>(
      wbuf, qkvwh, qkvwl, qkv_b, qkvb, nullptr, TOKP, 1152, 384, 384, 1);

  // attention, all batches: 2592 blocks; writes attn-out back into wbuf
  attn_kernel<<<BATCH*NWc*HEADS, 256, 0, stream>>>(qkvb, rpb, wbuf);

  // K1b: rebuild fp32 residual z (overlays now-dead qkvb)
  k1b_kernel<<<TOKC, 384, 0, stream>>>(x, g, norm_w, norm_b, musig, z);

  // proj GEMM + window-reverse/unshift scatter-add into z
  mfma_gemm<1><<<dim3(3, 249), 256, 0, stream>>>(
      wbuf, pwh, pwl, proj_b, nullptr, z, TOKP, 384, 384, 384, 1);

  // LN (n2): z -> wbuf rows 0..28799 (bf16)
  ln2_kernel<<<TOKC, 384, 0, stream>>>(z, n2_w, n2_b, wbuf);

  // MLP split along hidden dim: 4 col-chunks of 384; fc2 partials accumulate into z (residual inherent)
  for (int h0 = 0; h0 < MLPH; h0 += 384) {
    mfma_gemm<2><<<dim3(3, 225), 256, 0, stream>>>(
        wbuf, f1wh + (size_t)h0*384, f1wl + (size_t)h0*384, fc1_b + h0,
        hid, nullptr, TOKC, 384, 384, 384, 1);
    mfma_gemm<3><<<dim3(3, 225), 256, 0, stream>>>(
        hid, f2wh + h0, f2wl + h0, fc2_b,
        nullptr, z, TOKC, 384, 384, MLPH, h0 == 0 ? 1 : 0);
  }

  // y (=z) fp32 -> bf16 into wbuf for conv A-staging
  f2bf_kernel<<<(TOKC*C2c/4 + 255)/256, 256, 0, stream>>>(z, wbuf, TOKC*C2c/4);

  // conv 3x3 im2col MFMA + conv_b + x residual -> NCHW out
  mfma_conv<<<dim3(2, 225), 256, 0, stream>>>(wbuf, cvwh, cvwl, conv_b, x, outp);
}

// Round 7
// 872.489 us; speedup vs baseline: 4.4425x; 1.2687x over previous
//
#include <hip/hip_runtime.h>
#include <cstddef>
#include <cstdint>

// ---------------- problem constants ----------------
#define HEADS   4
#define C2c     384
#define HPc     63
#define WPc     63
#define NWc     81
#define BATCH   8
#define TOKP    (BATCH*HPc*WPc)   // 31752 windowed rows
#define TOKC    (BATCH*60*60)     // 28800 cropped tokens
#define MLPH    1536
#define TPB     3969              // windowed rows per batch
#define CONVK   3456              // 384*9
#define CONVN   192

typedef __attribute__((ext_vector_type(8))) short short8;
typedef __attribute__((ext_vector_type(4))) float f32x4;
typedef unsigned short u16;

__device__ __forceinline__ u16 f2bf(float f) {
  unsigned u = __float_as_uint(f);
  u += 0x7fff + ((u >> 16) & 1);           // RNE
  return (u16)(u >> 16);
}
__device__ __forceinline__ float bf2f(u16 b) { return __uint_as_float((unsigned)b << 16); }

// global -> LDS async 16B: dest = wave-uniform base + lane*16; src per-lane
#define GLOAD16(gp, lp) __builtin_amdgcn_global_load_lds( \
    (const __attribute__((address_space(1))) unsigned*)(gp), \
    (__attribute__((address_space(3))) unsigned*)(lp), 16, 0, 0)

// ---------------- block reduce (384 threads, 6 waves) ----------------
__device__ __forceinline__ float2 block_reduce_384(float v, float* red) {
  __syncthreads();
  float s = v, q = v * v;
  #pragma unroll
  for (int o = 32; o > 0; o >>= 1) {
    s += __shfl_down(s, o);
    q += __shfl_down(q, o);
  }
  int w = threadIdx.x >> 6;
  if ((threadIdx.x & 63) == 0) { red[2*w] = s; red[2*w+1] = q; }
  __syncthreads();
  float ts = red[0]+red[2]+red[4]+red[6]+red[8]+red[10];
  float tq = red[1]+red[3]+red[5]+red[7]+red[9]+red[11];
  return make_float2(ts, tq);
}

// ---------------- K1a: concat+pad -> LN(norm) [store mu,rsig]; LN(n1)+roll+window -> wbuf bf16 ----------------
__global__ __launch_bounds__(384)
void k1a_kernel(const float* __restrict__ x, const float* __restrict__ g,
                const float* __restrict__ nw, const float* __restrict__ nb,
                const float* __restrict__ n1w, const float* __restrict__ n1b,
                float* __restrict__ musig, u16* __restrict__ wbuf)
{
  __shared__ float red[12];
  int t = blockIdx.x;
  int b = t / (HPc*WPc);
  int rem = t - b*(HPc*WPc);
  int i = rem / WPc, j = rem - (rem / WPc)*WPc;
  int c = threadIdx.x;

  float v = 0.f;
  if (i < 60 && j < 60) {
    if (c < 192) v = x[(((size_t)b*192 + c)*60 + i)*60 + j];
    else         v = g[(((size_t)b*192 + (c-192))*60 + i)*60 + j];
  }
  float2 ss = block_reduce_384(v, red);
  float mu  = ss.x * (1.f/384.f);
  float var = ss.y * (1.f/384.f) - mu*mu;
  float rs  = rsqrtf(var + 1e-5f);
  if (c == 0) { musig[2*t] = mu; musig[2*t+1] = rs; }
  float zi  = (v - mu) * rs * nw[c] + nb[c];
  float2 s2 = block_reduce_384(zi, red);
  float mu2  = s2.x * (1.f/384.f);
  float var2 = s2.y * (1.f/384.f) - mu2*mu2;
  float zn = (zi - mu2) * rsqrtf(var2 + 1e-5f) * n1w[c] + n1b[c];
  int ai = i - 3; if (ai < 0) ai += HPc;
  int aj = j - 3; if (aj < 0) aj += WPc;
  int win = (ai/7)*9 + (aj/7);
  int tok = (ai%7)*7 + (aj%7);
  wbuf[(((size_t)b*NWc + win)*49 + tok)*C2c + c] = f2bf(zn);
}

// ---------------- K1b: recompute z fp32 (cropped) from x,g and stored mu/rsig ----------------
__global__ __launch_bounds__(384)
void k1b_kernel(const float* __restrict__ x, const float* __restrict__ g,
                const float* __restrict__ nw, const float* __restrict__ nb,
                const float* __restrict__ musig, float* __restrict__ z)
{
  int tc = blockIdx.x;
  int b = tc / 3600;
  int rem = tc - b*3600;
  int i = rem / 60, j = rem - (rem/60)*60;
  int t = b*(HPc*WPc) + i*WPc + j;          // padded token id
  int c = threadIdx.x;
  float v;
  if (c < 192) v = x[(((size_t)b*192 + c)*60 + i)*60 + j];
  else         v = g[(((size_t)b*192 + (c-192))*60 + i)*60 + j];
  float mu = musig[2*t], rs = musig[2*t+1];
  z[(size_t)tc*C2c + c] = (v - mu) * rs * nw[c] + nb[c];
}

// ---------------- LN (n2): z fp32 -> out bf16 ----------------
__global__ __launch_bounds__(384)
void ln2_kernel(const float* __restrict__ z, const float* __restrict__ nw,
                const float* __restrict__ nb, u16* __restrict__ out)
{
  __shared__ float red[12];
  int tc = blockIdx.x;
  int c = threadIdx.x;
  float v = z[(size_t)tc*C2c + c];
  float2 ss = block_reduce_384(v, red);
  float mu  = ss.x * (1.f/384.f);
  float var = ss.y * (1.f/384.f) - mu*mu;
  out[(size_t)tc*C2c + c] = f2bf((v - mu) * rsqrtf(var + 1e-5f) * nw[c] + nb[c]);
}

// ---------------- fp32 -> bf16 bulk convert (also used for weight casts) ----------------
__global__ __launch_bounds__(256)
void f2bf_kernel(const float* __restrict__ in, u16* __restrict__ out, int n4)
{
  int t = blockIdx.x*256 + threadIdx.x;
  if (t >= n4) return;
  float4 v = ((const float4*)in)[t];
  ushort4 o;
  o.x = f2bf(v.x); o.y = f2bf(v.y); o.z = f2bf(v.z); o.w = f2bf(v.w);
  ((ushort4*)out)[t] = o;
}

// conv weight: transpose OIHW -> [oc][p*384+c], split hi/lo (conv keeps hi/lo: it dominates absmax)
__global__ void split_convw(const float* __restrict__ cw, u16* __restrict__ hi, u16* __restrict__ lo)
{
  int t = blockIdx.x*blockDim.x + threadIdx.x;
  if (t >= CONVN*CONVK) return;
  int oc = t / CONVK, k = t - oc*CONVK;
  int p = k / 384, c = k - p*384;
  float v = cw[((size_t)oc*384 + c)*9 + p];
  u16 h = f2bf(v);
  hi[t] = h;
  lo[t] = f2bf(v - bf2f(h));
}

// ---------------- MFMA GEMM: C[M,N] = A[M,K](bf16) @ B[rows N, stride ldb]^T + bias ----------------
// 128x128 tile, BK=64, 4 waves (2x2), 4x4 16x16 frags/wave, single bf16 weight term.
// LDS XOR swizzle: phys_slot = log_slot ^ (row&7), 16B slots, 128B rows.  K multiple of 64; lda == K.
// EPI 0: bf16 store (qkv)   EPI 1: scatter-add into z (proj: window-reverse + unshift + residual)
// EPI 2: GELU -> bf16 (fc1 col-chunk)  EPI 3: z[m*384+n] += val (+bias if addbias) (fc2 partial)
template<int EPI>
__global__ __launch_bounds__(256)
void mfma_gemm(const u16* __restrict__ A, const u16* __restrict__ B,
               const float* __restrict__ bias, u16* __restrict__ Cb, float* __restrict__ zbuf,
               int M, int N, int K, int ldb, int addbias)
{
  __shared__ u16 As [128*64];
  __shared__ u16 Bs [128*64];
  int tid = threadIdx.x;
  int lane = tid & 63, w = tid >> 6;
  int wr = w >> 1, wc = w & 1;
  int m0 = blockIdx.y * 128, n0 = blockIdx.x * 128;
  int srow = lane >> 3, sslot = (lane & 7) ^ srow;

  f32x4 acc[4][4];
  #pragma unroll
  for (int i = 0; i < 4; ++i)
    #pragma unroll
    for (int j = 0; j < 4; ++j) acc[i][j] = (f32x4){0.f,0.f,0.f,0.f};

  char* AsB = (char*)As; char* BsB = (char*)Bs;
  int r15 = lane & 15, kq = lane >> 4;

  for (int k0 = 0; k0 < K; k0 += 64) {
    #pragma unroll
    for (int i = 0; i < 4; ++i) {
      int rblk = w*4 + i;
      int ar = m0 + rblk*8 + srow; if (ar >= M) ar = M - 1;   // clamp: results discarded at store
      int br = n0 + rblk*8 + srow;                            // B row count is exact multiple of 128
      GLOAD16(A + (size_t)ar*K   + k0 + sslot*8, AsB + rblk*1024);
      GLOAD16(B + (size_t)br*ldb + k0 + sslot*8, BsB + rblk*1024);
    }
    __syncthreads();
    #pragma unroll
    for (int ks = 0; ks < 2; ++ks) {
      int slog = ks*4 + kq;
      short8 af[4], bf[4];
      #pragma unroll
      for (int mi = 0; mi < 4; ++mi) {
        int row = wr*64 + mi*16 + r15;
        af[mi] = *(const short8*)(AsB + row*128 + ((slog ^ (row&7))<<4));
      }
      #pragma unroll
      for (int ni = 0; ni < 4; ++ni) {
        int row = wc*64 + ni*16 + r15;
        bf[ni] = *(const short8*)(BsB + row*128 + ((slog ^ (row&7))<<4));
      }
      #pragma unroll
      for (int mi = 0; mi < 4; ++mi)
        #pragma unroll
        for (int ni = 0; ni < 4; ++ni)
          acc[mi][ni] = __builtin_amdgcn_mfma_f32_16x16x32_bf16(af[mi], bf[ni], acc[mi][ni], 0, 0, 0);
    }
    __syncthreads();
  }

  // epilogue: C row = m0 + wr*64 + mi*16 + fq*4 + j ; col = n0 + wc*64 + ni*16 + fr
  int fq = lane >> 4, fr = lane & 15;
  #pragma unroll
  for (int mi = 0; mi < 4; ++mi) {
    #pragma unroll
    for (int j = 0; j < 4; ++j) {
      int m = m0 + wr*64 + mi*16 + fq*4 + j;
      if (m >= M) continue;
      int zrow = 0; bool zok = true;
      if (EPI == 1) {
        int b = m / TPB;
        int rem = m - b*TPB;
        int win = rem / 49, tok = rem - (rem/49)*49;
        int wh = win/9, ww = win - (win/9)*9;
        int th = tok/7, tw = tok - (tok/7)*7;
        int oi = wh*7 + th + 3; if (oi >= HPc) oi -= HPc;
        int oj = ww*7 + tw + 3; if (oj >= WPc) oj -= WPc;
        zok = (oi < 60 && oj < 60);
        zrow = (b*60 + oi)*60 + oj;
      }
      #pragma unroll
      for (int ni = 0; ni < 4; ++ni) {
        int n = n0 + wc*64 + ni*16 + fr;
        float val = acc[mi][ni][j];
        if (EPI == 0) {
          Cb[(size_t)m*N + n] = f2bf(val + bias[n]);
        } else if (EPI == 1) {
          if (zok) zbuf[(size_t)zrow*C2c + n] += val + bias[n];
        } else if (EPI == 2) {
          float vv = val + bias[n];
          float ge = 0.5f*vv*(1.f + erff(vv*0.70710678118654752f));
          Cb[(size_t)m*N + n] = f2bf(ge);
        } else { // EPI == 3
          float vv = val + (addbias ? bias[n] : 0.f);
          zbuf[(size_t)m*C2c + n] += vv;
        }
      }
    }
  }
}

// ---------------- conv as im2col MFMA GEMM: M=28800 pix, BM=128, BN=64, K=3456, hi/lo weights ----------------
__global__ __launch_bounds__(256)
void mfma_conv(const u16* __restrict__ Y, const u16* __restrict__ Bh, const u16* __restrict__ Bl,
               const float* __restrict__ cb, const float* __restrict__ xres, float* __restrict__ outp)
{
  __shared__ u16 As [128*64];   // 16 KB
  __shared__ u16 Bsh[64*64];    //  8 KB
  __shared__ u16 Bsl[64*64];    //  8 KB  -> 32 KB total, 5 blocks/CU
  int tid = threadIdx.x;
  int lane = tid & 63, w = tid >> 6;
  int wr = w >> 1, wc = w & 1;
  int m0 = blockIdx.y * 128, n0 = blockIdx.x * 64;
  int srow = lane >> 3, sslot = (lane & 7) ^ srow;

  f32x4 acc[4][2];
  #pragma unroll
  for (int i = 0; i < 4; ++i)
    #pragma unroll
    for (int j = 0; j < 2; ++j) acc[i][j] = (f32x4){0.f,0.f,0.f,0.f};

  int rowA[4], pbA[4], ohA[4], owA[4];
  #pragma unroll
  for (int i = 0; i < 4; ++i) {
    int idx = i*256 + tid;
    rowA[i] = idx >> 3;
    int pix = m0 + rowA[i];
    int pb = pix / 3600;
    int prem = pix - pb*3600;
    pbA[i] = pb; ohA[i] = prem / 60; owA[i] = prem - (prem/60)*60;
  }

  char* AsB = (char*)As; char* BhB = (char*)Bsh; char* BlB = (char*)Bsl;
  int r15 = lane & 15, kq = lane >> 4;

  for (int k0 = 0; k0 < CONVK; k0 += 64) {
    int p  = k0 / 384;                 // constant within a BK tile (384 % 64 == 0)
    int c0 = k0 - p*384;
    int dh = p/3 - 1, dw = (p - (p/3)*3) - 1;
    #pragma unroll
    for (int i = 0; i < 2; ++i) {      // B: 64 rows = 8 chunks of 8 rows
      int rblk = w*2 + i;
      int br = n0 + rblk*8 + srow;     // always < 192
      GLOAD16(Bh + (size_t)br*CONVK + k0 + sslot*8, BhB + rblk*1024);
      GLOAD16(Bl + (size_t)br*CONVK + k0 + sslot*8, BlB + rblk*1024);
    }
    #pragma unroll
    for (int i = 0; i < 4; ++i) {      // A: reg-staged gather with swizzled LDS write
      int idx = i*256 + tid;
      int row = rowA[i], slot = idx & 7;
      int ih = ohA[i] + dh, iw = owA[i] + dw;
      int4 v = {0,0,0,0};
      if ((unsigned)ih < 60u && (unsigned)iw < 60u)
        v = *(const int4*)(Y + (size_t)(pbA[i]*3600 + ih*60 + iw)*C2c + c0 + slot*8);
      *(int4*)(AsB + row*128 + ((slot ^ (row&7))<<4)) = v;
    }
    __syncthreads();
    #pragma unroll
    for (int ks = 0; ks < 2; ++ks) {
      int slog = ks*4 + kq;
      short8 af[4], bh[2], bl[2];
      #pragma unroll
      for (int mi = 0; mi < 4; ++mi) {
        int row = wr*64 + mi*16 + r15;
        af[mi] = *(const short8*)(AsB + row*128 + ((slog ^ (row&7))<<4));
      }
      #pragma unroll
      for (int ni = 0; ni < 2; ++ni) {
        int row = wc*32 + ni*16 + r15;
        int off = row*128 + ((slog ^ (row&7))<<4);
        bh[ni] = *(const short8*)(BhB + off);
        bl[ni] = *(const short8*)(BlB + off);
      }
      #pragma unroll
      for (int mi = 0; mi < 4; ++mi)
        #pragma unroll
        for (int ni = 0; ni < 2; ++ni) {
          acc[mi][ni] = __builtin_amdgcn_mfma_f32_16x16x32_bf16(af[mi], bh[ni], acc[mi][ni], 0, 0, 0);
          acc[mi][ni] = __builtin_amdgcn_mfma_f32_16x16x32_bf16(af[mi], bl[ni], acc[mi][ni], 0, 0, 0);
        }
    }
    __syncthreads();
  }

  int fq = lane >> 4, fr = lane & 15;
  #pragma unroll
  for (int mi = 0; mi < 4; ++mi) {
    #pragma unroll
    for (int j = 0; j < 4; ++j) {
      int m = m0 + wr*64 + mi*16 + fq*4 + j;          // pixel id, always < 28800
      int pb = m / 3600;
      int rem = m - pb*3600;
      int oh = rem / 60, ow = rem - (rem/60)*60;
      #pragma unroll
      for (int ni = 0; ni < 2; ++ni) {
        int oc = n0 + wc*32 + ni*16 + fr;             // always < 192
        size_t oi = ((size_t)pb*192 + oc)*3600 + oh*60 + ow;
        outp[oi] = acc[mi][ni][j] + cb[oc] + xres[oi];
      }
    }
  }
}

// ---------------- windowed attention, register-tiled; one block per (batch-window, head) ----------------
#define QS_STRIDE 100
#define VS_STRIDE 104
#define SS_STRIDE 53

__global__ __launch_bounds__(256)
void attn_kernel(const u16* __restrict__ qkv, const float* __restrict__ rpb,
                 u16* __restrict__ out)
{
  __shared__ float qs[52*QS_STRIDE];
  __shared__ float ks[52*QS_STRIDE];   // K during QK^T, then V (stride 104)
  __shared__ float S[52*SS_STRIDE];
  int blk = blockIdx.x;
  int h   = blk & 3;
  int bw  = blk >> 2;                 // b*81 + win
  int win = bw % NWc;
  const u16* base = qkv + (size_t)bw*49*1152;
  int tid = threadIdx.x;

  // load Q,K (short8-vectorized)
  for (int t2 = tid; t2 < 588; t2 += 256) {            // 49 rows * 12 groups of 8
    int r = t2 / 12, dq = t2 - (t2/12)*12;
    short8 qv = *(const short8*)(base + r*1152 +       h*96 + dq*8);
    short8 kv = *(const short8*)(base + r*1152 + 384 + h*96 + dq*8);
    #pragma unroll
    for (int e = 0; e < 8; ++e) {
      qs[r*QS_STRIDE + dq*8 + e] = bf2f((u16)qv[e]);
      ks[r*QS_STRIDE + dq*8 + e] = bf2f((u16)kv[e]);
    }
  }
  __syncthreads();

  const float scale = 0.1020620726159657f;   // 96^-0.5
  int wh = win / 9, ww = win - (win/9)*9;

  // QK^T: 13x13 threads, 4x4 outputs each, k blocked by 4 (float4 LDS reads)
  if (tid < 169) {
    int tr = tid / 13, tc = tid - (tid/13)*13;
    int r0 = tr*4, c0 = tc*4;
    float a[4][4] = {};
    for (int k0 = 0; k0 < 96; k0 += 4) {
      float4 qv[4], kv4[4];
      #pragma unroll
      for (int i = 0; i < 4; ++i) qv[i]  = *(const float4*)&qs[(r0+i)*QS_STRIDE + k0];
      #pragma unroll
      for (int j = 0; j < 4; ++j) kv4[j] = *(const float4*)&ks[(c0+j)*QS_STRIDE + k0];
      #pragma unroll
      for (int i = 0; i < 4; ++i)
        #pragma unroll
        for (int j = 0; j < 4; ++j)
          a[i][j] += qv[i].x*kv4[j].x + qv[i].y*kv4[j].y + qv[i].z*kv4[j].z + qv[i].w*kv4[j].w;
    }
    #pragma unroll
    for (int i = 0; i < 4; ++i) {
      int r = r0 + i;
      if (r < 49) {
        int r1 = r/7, c1 = r - (r/7)*7;
        int hp1 = wh*7 + r1, wp1 = ww*7 + c1;
        int g1 = (hp1 < 56 ? 0 : (hp1 < 60 ? 1 : 2))*3 + (wp1 < 56 ? 0 : (wp1 < 60 ? 1 : 2));
        #pragma unroll
        for (int j = 0; j < 4; ++j) {
          int c = c0 + j;
          if (c < 49) {
            int r2 = c/7, c2 = c - (c/7)*7;
            float s = a[i][j]*scale + rpb[((r1 - r2 + 6)*13 + (c1 - c2 + 6))*HEADS + h];
            int hp2 = wh*7 + r2, wp2 = ww*7 + c2;
            int g2 = (hp2 < 56 ? 0 : (hp2 < 60 ? 1 : 2))*3 + (wp2 < 56 ? 0 : (wp2 < 60 ? 1 : 2));
            if (g1 != g2) s -= 100.f;
            S[r*SS_STRIDE + c] = s;
          }
        }
      }
    }
  }
  __syncthreads();

  // V load (into ks, stride 104) overlapped with softmax (tid<49, disjoint rows of S)
  for (int t2 = tid; t2 < 588; t2 += 256) {
    int r = t2 / 12, dq = t2 - (t2/12)*12;
    short8 vv = *(const short8*)(base + r*1152 + 768 + h*96 + dq*8);
    #pragma unroll
    for (int e = 0; e < 8; ++e) ks[r*VS_STRIDE + dq*8 + e] = bf2f((u16)vv[e]);
  }
  if (tid < 49) {
    float mx = -1e30f;
    for (int c = 0; c < 49; ++c) mx = fmaxf(mx, S[tid*SS_STRIDE + c]);
    float sum = 0.f;
    for (int c = 0; c < 49; ++c) { float e = expf(S[tid*SS_STRIDE + c] - mx); S[tid*SS_STRIDE + c] = e; sum += e; }
    float inv = 1.f / sum;
    for (int c = 0; c < 49; ++c) S[tid*SS_STRIDE + c] *= inv;
  }
  __syncthreads();

  // PV: 13x12 threads, 4 rows x 8 cols each (float4 V reads)
  if (tid < 156) {
    int tr2 = tid / 12, tc2 = tid - (tid/12)*12;
    int r0 = tr2*4, d0 = tc2*8;
    float o[4][8] = {};
    for (int c = 0; c < 49; ++c) {
      float4 v0 = *(const float4*)&ks[c*VS_STRIDE + d0];
      float4 v1 = *(const float4*)&ks[c*VS_STRIDE + d0 + 4];
      #pragma unroll
      for (int i = 0; i < 4; ++i) {
        float sv = S[(r0+i)*SS_STRIDE + c];
        o[i][0] += sv*v0.x; o[i][1] += sv*v0.y; o[i][2] += sv*v0.z; o[i][3] += sv*v0.w;
        o[i][4] += sv*v1.x; o[i][5] += sv*v1.y; o[i][6] += sv*v1.z; o[i][7] += sv*v1.w;
      }
    }
    #pragma unroll
    for (int i = 0; i < 4; ++i) {
      int r = r0 + i;
      if (r >= 49) continue;
      ushort4 w0, w1;
      w0.x = f2bf(o[i][0]); w0.y = f2bf(o[i][1]); w0.z = f2bf(o[i][2]); w0.w = f2bf(o[i][3]);
      w1.x = f2bf(o[i][4]); w1.y = f2bf(o[i][5]); w1.z = f2bf(o[i][6]); w1.w = f2bf(o[i][7]);
      size_t ob = ((size_t)bw*49 + r)*C2c + h*96 + d0;
      *(ushort4*)&out[ob]     = w0;
      *(ushort4*)&out[ob + 4] = w1;
    }
  }
}

// ---------------- host launcher ----------------
extern "C" void kernel_launch(void* const* d_in, const int* in_sizes, int n_in,
                              void* d_out, int out_size, void* d_ws, size_t ws_size,
                              hipStream_t stream)
{
  const float* x      = (const float*)d_in[0];
  const float* g      = (const float*)d_in[1];
  const float* norm_w = (const float*)d_in[2];
  const float* norm_b = (const float*)d_in[3];
  const float* n1_w   = (const float*)d_in[4];
  const float* n1_b   = (const float*)d_in[5];
  const float* qkv_w  = (const float*)d_in[6];
  const float* qkv_b  = (const float*)d_in[7];
  const float* proj_w = (const float*)d_in[8];
  const float* proj_b = (const float*)d_in[9];
  const float* rpb    = (const float*)d_in[10];
  const float* n2_w   = (const float*)d_in[11];
  const float* n2_b   = (const float*)d_in[12];
  const float* fc1_w  = (const float*)d_in[13];
  const float* fc1_b  = (const float*)d_in[14];
  const float* fc2_w  = (const float*)d_in[15];
  const float* fc2_b  = (const float*)d_in[16];
  const float* conv_w = (const float*)d_in[17];
  const float* conv_b = (const float*)d_in[18];
  float* outp = (float*)d_out;

  // ---- workspace: ~104 MB ----
  char* p = (char*)d_ws;
  u16* wbuf = (u16*)p;              p += (size_t)TOKP*C2c*2;        // 24.39 MB zn-window -> attn-out -> ln2-out -> y(bf16)
  char* qr  = p;                    p += (size_t)TOKP*1152*2;       // 73.16 MB qkv bf16 (phase 1)
  u16*   qkvb = (u16*)qr;
  float* z    = (float*)qr;                                          // 44.24 MB fp32 residual (phase 2, overlays qkvb)
  u16*   hid  = (u16*)(qr + (size_t)TOKC*C2c*4);                     // 22.12 MB MLP hidden col-chunk (phase 2)
  u16* qkvw = (u16*)p; p += 442368*2;
  u16* pw   = (u16*)p; p += 147456*2;
  u16* f1w  = (u16*)p; p += 589824*2;
  u16* f2w  = (u16*)p; p += 589824*2;
  u16* cvwh = (u16*)p; p += (size_t)CONVN*CONVK*2;
  u16* cvwl = (u16*)p; p += (size_t)CONVN*CONVK*2;
  float* musig = (float*)p; p += (size_t)TOKP*2*4;

  // weight casts (single bf16) + conv hi/lo split
  f2bf_kernel<<<(442368/4 + 255)/256, 256, 0, stream>>>(qkv_w, qkvw, 442368/4);
  f2bf_kernel<<<(147456/4 + 255)/256, 256, 0, stream>>>(proj_w, pw, 147456/4);
  f2bf_kernel<<<(589824/4 + 255)/256, 256, 0, stream>>>(fc1_w, f1w, 589824/4);
  f2bf_kernel<<<(589824/4 + 255)/256, 256, 0, stream>>>(fc2_w, f2w, 589824/4);
  split_convw<<<(CONVN*CONVK + 255)/256, 256, 0, stream>>>(conv_w, cvwh, cvwl);

  // K1a: LN1 stats + LN(n1)+roll+window -> wbuf
  k1a_kernel<<<TOKP, 384, 0, stream>>>(x, g, norm_w, norm_b, n1_w, n1_b, musig, wbuf);

  // qkv GEMM, all batches: [31752,384] @ [1152,384]^T -> bf16
  mfma_gemm<0><<<dim3(9, 249), 256, 0, stream>>>(
      wbuf, qkvw, qkv_b, qkvb, nullptr, TOKP, 1152, 384, 384, 1);

  // attention, all batches: 2592 blocks; writes attn-out back into wbuf
  attn_kernel<<<BATCH*NWc*HEADS, 256, 0, stream>>>(qkvb, rpb, wbuf);

  // K1b: rebuild fp32 residual z (overlays now-dead qkvb)
  k1b_kernel<<<TOKC, 384, 0, stream>>>(x, g, norm_w, norm_b, musig, z);

  // proj GEMM + window-reverse/unshift scatter-add into z
  mfma_gemm<1><<<dim3(3, 249), 256, 0, stream>>>(
      wbuf, pw, proj_b, nullptr, z, TOKP, 384, 384, 384, 1);

  // LN (n2): z -> wbuf rows 0..28799 (bf16)
  ln2_kernel<<<TOKC, 384, 0, stream>>>(z, n2_w, n2_b, wbuf);

  // MLP split along hidden dim: 4 col-chunks of 384; fc2 partials accumulate into z (residual inherent)
  for (int h0 = 0; h0 < MLPH; h0 += 384) {
    mfma_gemm<2><<<dim3(3, 225), 256, 0, stream>>>(
        wbuf, f1w + (size_t)h0*384, fc1_b + h0,
        hid, nullptr, TOKC, 384, 384, 384, 1);
    mfma_gemm<3><<<dim3(3, 225), 256, 0, stream>>>(
        hid, f2w + h0, fc2_b,
        nullptr, z, TOKC, 384, 384, MLPH, h0 == 0 ? 1 : 0);
  }

  // y (=z) fp32 -> bf16 into wbuf for conv A-staging
  f2bf_kernel<<<(TOKC*C2c/4 + 255)/256, 256, 0, stream>>>(z, wbuf, TOKC*C2c/4);

  // conv 3x3 im2col MFMA (BM=128, BN=64) + conv_b + x residual -> NCHW out
  mfma_conv<<<dim3(3, 225), 256, 0, stream>>>(wbuf, cvwh, cvwl, conv_b, x, outp);
}

// Round 8
// 747.256 us; speedup vs baseline: 5.1870x; 1.1676x over previous
//
#include <hip/hip_runtime.h>
#include <cstddef>
#include <cstdint>

// ---------------- problem constants ----------------
#define HEADS   4
#define C2c     384
#define HPc     63
#define WPc     63
#define NWc     81
#define BATCH   8
#define TOKP    (BATCH*HPc*WPc)   // 31752 windowed rows
#define TOKC    (BATCH*60*60)     // 28800 cropped tokens
#define MLPH    1536
#define TPB     3969              // windowed rows per batch
#define CONVK   3456              // 384*9
#define CONVN   192

typedef __attribute__((ext_vector_type(8))) short short8;
typedef __attribute__((ext_vector_type(4))) float f32x4;
typedef unsigned short u16;

__device__ __forceinline__ u16 f2bf(float f) {
  unsigned u = __float_as_uint(f);
  u += 0x7fff + ((u >> 16) & 1);           // RNE
  return (u16)(u >> 16);
}
__device__ __forceinline__ float bf2f(u16 b) { return __uint_as_float((unsigned)b << 16); }

// global -> LDS async 16B: dest = wave-uniform base + lane*16; src per-lane
#define GLOAD16(gp, lp) __builtin_amdgcn_global_load_lds( \
    (const __attribute__((address_space(1))) unsigned*)(gp), \
    (__attribute__((address_space(3))) unsigned*)(lp), 16, 0, 0)

// bijective XCD swizzle (m204): HW round-robins consecutive IDs across 8 XCDs;
// remap so each XCD processes a CONTIGUOUS range of logical tiles (L2 locality).
__device__ __forceinline__ int xcd_swizzle(int orig, int nwg) {
  int q = nwg >> 3, r = nwg & 7;
  int xcd = orig & 7, off = orig >> 3;
  return (xcd < r ? xcd*(q+1) : r*(q+1) + (xcd - r)*q) + off;
}

// ---------------- block reduce (384 threads, 6 waves) ----------------
__device__ __forceinline__ float2 block_reduce_384(float v, float* red) {
  __syncthreads();
  float s = v, q = v * v;
  #pragma unroll
  for (int o = 32; o > 0; o >>= 1) {
    s += __shfl_down(s, o);
    q += __shfl_down(q, o);
  }
  int w = threadIdx.x >> 6;
  if ((threadIdx.x & 63) == 0) { red[2*w] = s; red[2*w+1] = q; }
  __syncthreads();
  float ts = red[0]+red[2]+red[4]+red[6]+red[8]+red[10];
  float tq = red[1]+red[3]+red[5]+red[7]+red[9]+red[11];
  return make_float2(ts, tq);
}

// ---------------- K1a: concat+pad -> LN(norm) [store mu,rsig]; LN(n1)+roll+window -> wbuf bf16 ----------------
__global__ __launch_bounds__(384)
void k1a_kernel(const float* __restrict__ x, const float* __restrict__ g,
                const float* __restrict__ nw, const float* __restrict__ nb,
                const float* __restrict__ n1w, const float* __restrict__ n1b,
                float* __restrict__ musig, u16* __restrict__ wbuf)
{
  __shared__ float red[12];
  int t = blockIdx.x;
  int b = t / (HPc*WPc);
  int rem = t - b*(HPc*WPc);
  int i = rem / WPc, j = rem - (rem / WPc)*WPc;
  int c = threadIdx.x;

  float v = 0.f;
  if (i < 60 && j < 60) {
    if (c < 192) v = x[(((size_t)b*192 + c)*60 + i)*60 + j];
    else         v = g[(((size_t)b*192 + (c-192))*60 + i)*60 + j];
  }
  float2 ss = block_reduce_384(v, red);
  float mu  = ss.x * (1.f/384.f);
  float var = ss.y * (1.f/384.f) - mu*mu;
  float rs  = rsqrtf(var + 1e-5f);
  if (c == 0) { musig[2*t] = mu; musig[2*t+1] = rs; }
  float zi  = (v - mu) * rs * nw[c] + nb[c];
  float2 s2 = block_reduce_384(zi, red);
  float mu2  = s2.x * (1.f/384.f);
  float var2 = s2.y * (1.f/384.f) - mu2*mu2;
  float zn = (zi - mu2) * rsqrtf(var2 + 1e-5f) * n1w[c] + n1b[c];
  int ai = i - 3; if (ai < 0) ai += HPc;
  int aj = j - 3; if (aj < 0) aj += WPc;
  int win = (ai/7)*9 + (aj/7);
  int tok = (ai%7)*7 + (aj%7);
  wbuf[(((size_t)b*NWc + win)*49 + tok)*C2c + c] = f2bf(zn);
}

// ---------------- K1b: recompute z fp32 (cropped) from x,g and stored mu/rsig ----------------
__global__ __launch_bounds__(384)
void k1b_kernel(const float* __restrict__ x, const float* __restrict__ g,
                const float* __restrict__ nw, const float* __restrict__ nb,
                const float* __restrict__ musig, float* __restrict__ z)
{
  int tc = blockIdx.x;
  int b = tc / 3600;
  int rem = tc - b*3600;
  int i = rem / 60, j = rem - (rem/60)*60;
  int t = b*(HPc*WPc) + i*WPc + j;          // padded token id
  int c = threadIdx.x;
  float v;
  if (c < 192) v = x[(((size_t)b*192 + c)*60 + i)*60 + j];
  else         v = g[(((size_t)b*192 + (c-192))*60 + i)*60 + j];
  float mu = musig[2*t], rs = musig[2*t+1];
  z[(size_t)tc*C2c + c] = (v - mu) * rs * nw[c] + nb[c];
}

// ---------------- LN (n2): z fp32 -> out bf16 ----------------
__global__ __launch_bounds__(384)
void ln2_kernel(const float* __restrict__ z, const float* __restrict__ nw,
                const float* __restrict__ nb, u16* __restrict__ out)
{
  __shared__ float red[12];
  int tc = blockIdx.x;
  int c = threadIdx.x;
  float v = z[(size_t)tc*C2c + c];
  float2 ss = block_reduce_384(v, red);
  float mu  = ss.x * (1.f/384.f);
  float var = ss.y * (1.f/384.f) - mu*mu;
  out[(size_t)tc*C2c + c] = f2bf((v - mu) * rsqrtf(var + 1e-5f) * nw[c] + nb[c]);
}

// ---------------- fp32 -> bf16 bulk convert (weight casts) ----------------
__global__ __launch_bounds__(256)
void f2bf_kernel(const float* __restrict__ in, u16* __restrict__ out, int n4)
{
  int t = blockIdx.x*256 + threadIdx.x;
  if (t >= n4) return;
  float4 v = ((const float4*)in)[t];
  ushort4 o;
  o.x = f2bf(v.x); o.y = f2bf(v.y); o.z = f2bf(v.z); o.w = f2bf(v.w);
  ((ushort4*)out)[t] = o;
}

// conv weight: transpose OIHW -> [oc][p*384+c], split hi/lo (conv keeps hi/lo: it dominates absmax)
__global__ void split_convw(const float* __restrict__ cw, u16* __restrict__ hi, u16* __restrict__ lo)
{
  int t = blockIdx.x*blockDim.x + threadIdx.x;
  if (t >= CONVN*CONVK) return;
  int oc = t / CONVK, k = t - oc*CONVK;
  int p = k / 384, c = k - p*384;
  float v = cw[((size_t)oc*384 + c)*9 + p];
  u16 h = f2bf(v);
  hi[t] = h;
  lo[t] = f2bf(v - bf2f(h));
}

// ---------------- MFMA GEMM: C[M,N] = A[M,K](bf16) @ B[rows N, stride ldb]^T + bias ----------------
// 128x128 tile, BK=64, 4 waves (2x2), single bf16 weight term, XCD-swizzled block mapping.
// EPI 0: bf16 store (qkv)   EPI 1: scatter-add into z (proj: window-reverse + unshift + residual)
// EPI 2: GELU -> bf16 (fc1) EPI 3: z += val(+bias) (fc2 partial)
// EPI 4: vv = val(+bias)+z; z = vv; Cb bf16 = vv  (final fc2, fused y-cast)
template<int EPI>
__global__ __launch_bounds__(256)
void mfma_gemm(const u16* __restrict__ A, const u16* __restrict__ B,
               const float* __restrict__ bias, u16* __restrict__ Cb, float* __restrict__ zbuf,
               int M, int N, int K, int ldb, int addbias)
{
  __shared__ u16 As [128*64];
  __shared__ u16 Bs [128*64];
  int tid = threadIdx.x;
  int lane = tid & 63, w = tid >> 6;
  int wr = w >> 1, wc = w & 1;
  int nwg = gridDim.x * gridDim.y;
  int swz = xcd_swizzle(blockIdx.y*gridDim.x + blockIdx.x, nwg);
  int bx = swz % gridDim.x, by = swz / gridDim.x;
  int m0 = by * 128, n0 = bx * 128;
  int srow = lane >> 3, sslot = (lane & 7) ^ srow;

  f32x4 acc[4][4];
  #pragma unroll
  for (int i = 0; i < 4; ++i)
    #pragma unroll
    for (int j = 0; j < 4; ++j) acc[i][j] = (f32x4){0.f,0.f,0.f,0.f};

  char* AsB = (char*)As; char* BsB = (char*)Bs;
  int r15 = lane & 15, kq = lane >> 4;

  for (int k0 = 0; k0 < K; k0 += 64) {
    #pragma unroll
    for (int i = 0; i < 4; ++i) {
      int rblk = w*4 + i;
      int ar = m0 + rblk*8 + srow; if (ar >= M) ar = M - 1;   // clamp: results discarded at store
      int br = n0 + rblk*8 + srow;                            // B row count is exact multiple of 128
      GLOAD16(A + (size_t)ar*K   + k0 + sslot*8, AsB + rblk*1024);
      GLOAD16(B + (size_t)br*ldb + k0 + sslot*8, BsB + rblk*1024);
    }
    __syncthreads();
    #pragma unroll
    for (int ks = 0; ks < 2; ++ks) {
      int slog = ks*4 + kq;
      short8 af[4], bf[4];
      #pragma unroll
      for (int mi = 0; mi < 4; ++mi) {
        int row = wr*64 + mi*16 + r15;
        af[mi] = *(const short8*)(AsB + row*128 + ((slog ^ (row&7))<<4));
      }
      #pragma unroll
      for (int ni = 0; ni < 4; ++ni) {
        int row = wc*64 + ni*16 + r15;
        bf[ni] = *(const short8*)(BsB + row*128 + ((slog ^ (row&7))<<4));
      }
      #pragma unroll
      for (int mi = 0; mi < 4; ++mi)
        #pragma unroll
        for (int ni = 0; ni < 4; ++ni)
          acc[mi][ni] = __builtin_amdgcn_mfma_f32_16x16x32_bf16(af[mi], bf[ni], acc[mi][ni], 0, 0, 0);
    }
    __syncthreads();
  }

  // epilogue: C row = m0 + wr*64 + mi*16 + fq*4 + j ; col = n0 + wc*64 + ni*16 + fr
  int fq = lane >> 4, fr = lane & 15;
  #pragma unroll
  for (int mi = 0; mi < 4; ++mi) {
    #pragma unroll
    for (int j = 0; j < 4; ++j) {
      int m = m0 + wr*64 + mi*16 + fq*4 + j;
      if (m >= M) continue;
      int zrow = 0; bool zok = true;
      if (EPI == 1) {
        int b = m / TPB;
        int rem = m - b*TPB;
        int win = rem / 49, tok = rem - (rem/49)*49;
        int wh = win/9, ww = win - (win/9)*9;
        int th = tok/7, tw = tok - (tok/7)*7;
        int oi = wh*7 + th + 3; if (oi >= HPc) oi -= HPc;
        int oj = ww*7 + tw + 3; if (oj >= WPc) oj -= WPc;
        zok = (oi < 60 && oj < 60);
        zrow = (b*60 + oi)*60 + oj;
      }
      #pragma unroll
      for (int ni = 0; ni < 4; ++ni) {
        int n = n0 + wc*64 + ni*16 + fr;
        float val = acc[mi][ni][j];
        if (EPI == 0) {
          Cb[(size_t)m*N + n] = f2bf(val + bias[n]);
        } else if (EPI == 1) {
          if (zok) zbuf[(size_t)zrow*C2c + n] += val + bias[n];
        } else if (EPI == 2) {
          float vv = val + bias[n];
          float ge = 0.5f*vv*(1.f + erff(vv*0.70710678118654752f));
          Cb[(size_t)m*N + n] = f2bf(ge);
        } else if (EPI == 3) {
          float vv = val + (addbias ? bias[n] : 0.f);
          zbuf[(size_t)m*C2c + n] += vv;
        } else { // EPI == 4: final fc2 — z update + fused bf16 y store
          float vv = val + (addbias ? bias[n] : 0.f) + zbuf[(size_t)m*C2c + n];
          zbuf[(size_t)m*C2c + n] = vv;
          Cb[(size_t)m*C2c + n] = f2bf(vv);
        }
      }
    }
  }
}

// ---------------- conv as im2col MFMA GEMM: BM=64, BN=64, K=3456, hi/lo weights, XCD swizzle ----------------
__global__ __launch_bounds__(256)
void mfma_conv(const u16* __restrict__ Y, const u16* __restrict__ Bh, const u16* __restrict__ Bl,
               const float* __restrict__ cb, const float* __restrict__ xres, float* __restrict__ outp)
{
  __shared__ u16 As [64*64];    //  8 KB
  __shared__ u16 Bsh[64*64];    //  8 KB
  __shared__ u16 Bsl[64*64];    //  8 KB  -> 24 KB total
  int tid = threadIdx.x;
  int lane = tid & 63, w = tid >> 6;
  int wr = w >> 1, wc = w & 1;
  int nwg = gridDim.x * gridDim.y;   // 3*450 = 1350
  int swz = xcd_swizzle(blockIdx.y*gridDim.x + blockIdx.x, nwg);
  int bx = swz % 3, by = swz / 3;
  int m0 = by * 64, n0 = bx * 64;
  int srow = lane >> 3, sslot = (lane & 7) ^ srow;

  f32x4 acc[2][2];
  #pragma unroll
  for (int i = 0; i < 2; ++i)
    #pragma unroll
    for (int j = 0; j < 2; ++j) acc[i][j] = (f32x4){0.f,0.f,0.f,0.f};

  int rowA[2], pbA[2], ohA[2], owA[2];
  #pragma unroll
  for (int i = 0; i < 2; ++i) {
    int idx = i*256 + tid;
    rowA[i] = idx >> 3;
    int pix = m0 + rowA[i];
    int pb = pix / 3600;
    int prem = pix - pb*3600;
    pbA[i] = pb; ohA[i] = prem / 60; owA[i] = prem - (prem/60)*60;
  }

  char* AsB = (char*)As; char* BhB = (char*)Bsh; char* BlB = (char*)Bsl;
  int r15 = lane & 15, kq = lane >> 4;

  for (int k0 = 0; k0 < CONVK; k0 += 64) {
    int p  = k0 / 384;                 // constant within a BK tile (384 % 64 == 0)
    int c0 = k0 - p*384;
    int dh = p/3 - 1, dw = (p - (p/3)*3) - 1;
    #pragma unroll
    for (int i = 0; i < 2; ++i) {      // B: 64 rows = 8 chunks of 8 rows
      int rblk = w*2 + i;
      int br = n0 + rblk*8 + srow;     // always < 192
      GLOAD16(Bh + (size_t)br*CONVK + k0 + sslot*8, BhB + rblk*1024);
      GLOAD16(Bl + (size_t)br*CONVK + k0 + sslot*8, BlB + rblk*1024);
    }
    #pragma unroll
    for (int i = 0; i < 2; ++i) {      // A: reg-staged gather with swizzled LDS write
      int idx = i*256 + tid;
      int row = rowA[i], slot = idx & 7;
      int ih = ohA[i] + dh, iw = owA[i] + dw;
      int4 v = {0,0,0,0};
      if ((unsigned)ih < 60u && (unsigned)iw < 60u)
        v = *(const int4*)(Y + (size_t)(pbA[i]*3600 + ih*60 + iw)*C2c + c0 + slot*8);
      *(int4*)(AsB + row*128 + ((slot ^ (row&7))<<4)) = v;
    }
    __syncthreads();
    #pragma unroll
    for (int ks = 0; ks < 2; ++ks) {
      int slog = ks*4 + kq;
      short8 af[2], bh[2], bl[2];
      #pragma unroll
      for (int mi = 0; mi < 2; ++mi) {
        int row = wr*32 + mi*16 + r15;
        af[mi] = *(const short8*)(AsB + row*128 + ((slog ^ (row&7))<<4));
      }
      #pragma unroll
      for (int ni = 0; ni < 2; ++ni) {
        int row = wc*32 + ni*16 + r15;
        int off = row*128 + ((slog ^ (row&7))<<4);
        bh[ni] = *(const short8*)(BhB + off);
        bl[ni] = *(const short8*)(BlB + off);
      }
      #pragma unroll
      for (int mi = 0; mi < 2; ++mi)
        #pragma unroll
        for (int ni = 0; ni < 2; ++ni) {
          acc[mi][ni] = __builtin_amdgcn_mfma_f32_16x16x32_bf16(af[mi], bh[ni], acc[mi][ni], 0, 0, 0);
          acc[mi][ni] = __builtin_amdgcn_mfma_f32_16x16x32_bf16(af[mi], bl[ni], acc[mi][ni], 0, 0, 0);
        }
    }
    __syncthreads();
  }

  int fq = lane >> 4, fr = lane & 15;
  #pragma unroll
  for (int mi = 0; mi < 2; ++mi) {
    #pragma unroll
    for (int j = 0; j < 4; ++j) {
      int m = m0 + wr*32 + mi*16 + fq*4 + j;          // pixel id, always < 28800
      int pb = m / 3600;
      int rem = m - pb*3600;
      int oh = rem / 60, ow = rem - (rem/60)*60;
      #pragma unroll
      for (int ni = 0; ni < 2; ++ni) {
        int oc = n0 + wc*32 + ni*16 + fr;             // always < 192
        size_t oi = ((size_t)pb*192 + oc)*3600 + oh*60 + ow;
        outp[oi] = acc[mi][ni][j] + cb[oc] + xres[oi];
      }
    }
  }
}

// ---------------- windowed attention, register-tiled; one block per (batch-window, head) ----------------
#define QS_STRIDE 100
#define VS_STRIDE 104
#define SS_STRIDE 53

__global__ __launch_bounds__(256)
void attn_kernel(const u16* __restrict__ qkv, const float* __restrict__ rpb,
                 u16* __restrict__ out)
{
  __shared__ float qs[52*QS_STRIDE];
  __shared__ float ks[52*QS_STRIDE];   // K during QK^T, then V (stride 104)
  __shared__ float S[52*SS_STRIDE];
  int blk = blockIdx.x;
  int h   = blk & 3;
  int bw  = blk >> 2;                 // b*81 + win
  int win = bw % NWc;
  const u16* base = qkv + (size_t)bw*49*1152;
  int tid = threadIdx.x;

  for (int t2 = tid; t2 < 588; t2 += 256) {            // 49 rows * 12 groups of 8
    int r = t2 / 12, dq = t2 - (t2/12)*12;
    short8 qv = *(const short8*)(base + r*1152 +       h*96 + dq*8);
    short8 kv = *(const short8*)(base + r*1152 + 384 + h*96 + dq*8);
    #pragma unroll
    for (int e = 0; e < 8; ++e) {
      qs[r*QS_STRIDE + dq*8 + e] = bf2f((u16)qv[e]);
      ks[r*QS_STRIDE + dq*8 + e] = bf2f((u16)kv[e]);
    }
  }
  __syncthreads();

  const float scale = 0.1020620726159657f;   // 96^-0.5
  int wh = win / 9, ww = win - (win/9)*9;

  if (tid < 169) {
    int tr = tid / 13, tc = tid - (tid/13)*13;
    int r0 = tr*4, c0 = tc*4;
    float a[4][4] = {};
    for (int k0 = 0; k0 < 96; k0 += 4) {
      float4 qv[4], kv4[4];
      #pragma unroll
      for (int i = 0; i < 4; ++i) qv[i]  = *(const float4*)&qs[(r0+i)*QS_STRIDE + k0];
      #pragma unroll
      for (int j = 0; j < 4; ++j) kv4[j] = *(const float4*)&ks[(c0+j)*QS_STRIDE + k0];
      #pragma unroll
      for (int i = 0; i < 4; ++i)
        #pragma unroll
        for (int j = 0; j < 4; ++j)
          a[i][j] += qv[i].x*kv4[j].x + qv[i].y*kv4[j].y + qv[i].z*kv4[j].z + qv[i].w*kv4[j].w;
    }
    #pragma unroll
    for (int i = 0; i < 4; ++i) {
      int r = r0 + i;
      if (r < 49) {
        int r1 = r/7, c1 = r - (r/7)*7;
        int hp1 = wh*7 + r1, wp1 = ww*7 + c1;
        int g1 = (hp1 < 56 ? 0 : (hp1 < 60 ? 1 : 2))*3 + (wp1 < 56 ? 0 : (wp1 < 60 ? 1 : 2));
        #pragma unroll
        for (int j = 0; j < 4; ++j) {
          int c = c0 + j;
          if (c < 49) {
            int r2 = c/7, c2 = c - (c/7)*7;
            float s = a[i][j]*scale + rpb[((r1 - r2 + 6)*13 + (c1 - c2 + 6))*HEADS + h];
            int hp2 = wh*7 + r2, wp2 = ww*7 + c2;
            int g2 = (hp2 < 56 ? 0 : (hp2 < 60 ? 1 : 2))*3 + (wp2 < 56 ? 0 : (wp2 < 60 ? 1 : 2));
            if (g1 != g2) s -= 100.f;
            S[r*SS_STRIDE + c] = s;
          }
        }
      }
    }
  }
  __syncthreads();

  for (int t2 = tid; t2 < 588; t2 += 256) {
    int r = t2 / 12, dq = t2 - (t2/12)*12;
    short8 vv = *(const short8*)(base + r*1152 + 768 + h*96 + dq*8);
    #pragma unroll
    for (int e = 0; e < 8; ++e) ks[r*VS_STRIDE + dq*8 + e] = bf2f((u16)vv[e]);
  }
  if (tid < 49) {
    float mx = -1e30f;
    for (int c = 0; c < 49; ++c) mx = fmaxf(mx, S[tid*SS_STRIDE + c]);
    float sum = 0.f;
    for (int c = 0; c < 49; ++c) { float e = expf(S[tid*SS_STRIDE + c] - mx); S[tid*SS_STRIDE + c] = e; sum += e; }
    float inv = 1.f / sum;
    for (int c = 0; c < 49; ++c) S[tid*SS_STRIDE + c] *= inv;
  }
  __syncthreads();

  if (tid < 156) {
    int tr2 = tid / 12, tc2 = tid - (tid/12)*12;
    int r0 = tr2*4, d0 = tc2*8;
    float o[4][8] = {};
    for (int c = 0; c < 49; ++c) {
      float4 v0 = *(const float4*)&ks[c*VS_STRIDE + d0];
      float4 v1 = *(const float4*)&ks[c*VS_STRIDE + d0 + 4];
      #pragma unroll
      for (int i = 0; i < 4; ++i) {
        float sv = S[(r0+i)*SS_STRIDE + c];
        o[i][0] += sv*v0.x; o[i][1] += sv*v0.y; o[i][2] += sv*v0.z; o[i][3] += sv*v0.w;
        o[i][4] += sv*v1.x; o[i][5] += sv*v1.y; o[i][6] += sv*v1.z; o[i][7] += sv*v1.w;
      }
    }
    #pragma unroll
    for (int i = 0; i < 4; ++i) {
      int r = r0 + i;
      if (r >= 49) continue;
      ushort4 w0, w1;
      w0.x = f2bf(o[i][0]); w0.y = f2bf(o[i][1]); w0.z = f2bf(o[i][2]); w0.w = f2bf(o[i][3]);
      w1.x = f2bf(o[i][4]); w1.y = f2bf(o[i][5]); w1.z = f2bf(o[i][6]); w1.w = f2bf(o[i][7]);
      size_t ob = ((size_t)bw*49 + r)*C2c + h*96 + d0;
      *(ushort4*)&out[ob]     = w0;
      *(ushort4*)&out[ob + 4] = w1;
    }
  }
}

// ---------------- host launcher ----------------
extern "C" void kernel_launch(void* const* d_in, const int* in_sizes, int n_in,
                              void* d_out, int out_size, void* d_ws, size_t ws_size,
                              hipStream_t stream)
{
  const float* x      = (const float*)d_in[0];
  const float* g      = (const float*)d_in[1];
  const float* norm_w = (const float*)d_in[2];
  const float* norm_b = (const float*)d_in[3];
  const float* n1_w   = (const float*)d_in[4];
  const float* n1_b   = (const float*)d_in[5];
  const float* qkv_w  = (const float*)d_in[6];
  const float* qkv_b  = (const float*)d_in[7];
  const float* proj_w = (const float*)d_in[8];
  const float* proj_b = (const float*)d_in[9];
  const float* rpb    = (const float*)d_in[10];
  const float* n2_w   = (const float*)d_in[11];
  const float* n2_b   = (const float*)d_in[12];
  const float* fc1_w  = (const float*)d_in[13];
  const float* fc1_b  = (const float*)d_in[14];
  const float* fc2_w  = (const float*)d_in[15];
  const float* fc2_b  = (const float*)d_in[16];
  const float* conv_w = (const float*)d_in[17];
  const float* conv_b = (const float*)d_in[18];
  float* outp = (float*)d_out;

  // ---- workspace base: ~99.2 MiB ----
  char* p = (char*)d_ws;
  u16* wbuf = (u16*)p;              p += (size_t)TOKP*C2c*2;        // zn-window -> attn-out -> ln2-out -> y(bf16)
  char* qr  = p;                    p += (size_t)TOKP*1152*2;       // qkv bf16 (phase 1)
  u16*   qkvb = (u16*)qr;
  float* z    = (float*)qr;                                          // fp32 residual (phase 2, overlays qkvb)
  u16*   hid_c = (u16*)(qr + (size_t)TOKC*C2c*4);                    // chunked MLP hidden (overlay)
  u16* qkvw = (u16*)p; p += 442368*2;
  u16* pw   = (u16*)p; p += 147456*2;
  u16* f1w  = (u16*)p; p += 589824*2;
  u16* f2w  = (u16*)p; p += 589824*2;
  u16* cvwh = (u16*)p; p += (size_t)CONVN*CONVK*2;
  u16* cvwl = (u16*)p; p += (size_t)CONVN*CONVK*2;
  float* musig = (float*)p; p += (size_t)TOKP*2*4;
  u16* hid_f = (u16*)p;                                              // full MLP hidden (88.5 MB) if ws allows
  size_t need_full = (size_t)(p - (char*)d_ws) + (size_t)TOKC*MLPH*2;
  bool full_mlp = ws_size >= need_full;

  // weight casts (single bf16) + conv hi/lo split
  f2bf_kernel<<<(442368/4 + 255)/256, 256, 0, stream>>>(qkv_w, qkvw, 442368/4);
  f2bf_kernel<<<(147456/4 + 255)/256, 256, 0, stream>>>(proj_w, pw, 147456/4);
  f2bf_kernel<<<(589824/4 + 255)/256, 256, 0, stream>>>(fc1_w, f1w, 589824/4);
  f2bf_kernel<<<(589824/4 + 255)/256, 256, 0, stream>>>(fc2_w, f2w, 589824/4);
  split_convw<<<(CONVN*CONVK + 255)/256, 256, 0, stream>>>(conv_w, cvwh, cvwl);

  // K1a: LN1 stats + LN(n1)+roll+window -> wbuf
  k1a_kernel<<<TOKP, 384, 0, stream>>>(x, g, norm_w, norm_b, n1_w, n1_b, musig, wbuf);

  // qkv GEMM, all batches: [31752,384] @ [1152,384]^T -> bf16
  mfma_gemm<0><<<dim3(9, 249), 256, 0, stream>>>(
      wbuf, qkvw, qkv_b, qkvb, nullptr, TOKP, 1152, 384, 384, 1);

  // attention, all batches: 2592 blocks; writes attn-out back into wbuf
  attn_kernel<<<BATCH*NWc*HEADS, 256, 0, stream>>>(qkvb, rpb, wbuf);

  // K1b: rebuild fp32 residual z (overlays now-dead qkvb)
  k1b_kernel<<<TOKC, 384, 0, stream>>>(x, g, norm_w, norm_b, musig, z);

  // proj GEMM + window-reverse/unshift scatter-add into z
  mfma_gemm<1><<<dim3(3, 249), 256, 0, stream>>>(
      wbuf, pw, proj_b, nullptr, z, TOKP, 384, 384, 384, 1);

  // LN (n2): z -> wbuf rows 0..28799 (bf16)
  ln2_kernel<<<TOKC, 384, 0, stream>>>(z, n2_w, n2_b, wbuf);

  if (full_mlp) {
    // one-shot MLP: fc1 full-N -> hid_f; fc2 full-K, z RMW once, fused y-bf16 into wbuf
    mfma_gemm<2><<<dim3(12, 225), 256, 0, stream>>>(
        wbuf, f1w, fc1_b, hid_f, nullptr, TOKC, MLPH, 384, 384, 1);
    mfma_gemm<4><<<dim3(3, 225), 256, 0, stream>>>(
        hid_f, f2w, fc2_b, wbuf, z, TOKC, 384, MLPH, MLPH, 1);
  } else {
    // fallback: hidden-dim split in 4 col-chunks; final chunk fuses y-bf16
    for (int h0 = 0; h0 < MLPH; h0 += 384) {
      mfma_gemm<2><<<dim3(3, 225), 256, 0, stream>>>(
          wbuf, f1w + (size_t)h0*384, fc1_b + h0,
          hid_c, nullptr, TOKC, 384, 384, 384, 1);
      if (h0 < MLPH - 384)
        mfma_gemm<3><<<dim3(3, 225), 256, 0, stream>>>(
            hid_c, f2w + h0, fc2_b,
            nullptr, z, TOKC, 384, 384, MLPH, h0 == 0 ? 1 : 0);
      else
        mfma_gemm<4><<<dim3(3, 225), 256, 0, stream>>>(
            hid_c, f2w + h0, fc2_b,
            wbuf, z, TOKC, 384, 384, MLPH, 0);
    }
  }

  // conv 3x3 im2col MFMA (BM=64, BN=64, XCD-swizzled) + conv_b + x residual -> NCHW out
  mfma_conv<<<dim3(3, 450), 256, 0, stream>>>(wbuf, cvwh, cvwl, conv_b, x, outp);
}

// Round 9
// 745.394 us; speedup vs baseline: 5.2000x; 1.0025x over previous
//
#include <hip/hip_runtime.h>
#include <cstddef>
#include <cstdint>

// ---------------- problem constants ----------------
#define HEADS   4
#define C2c     384
#define HPc     63
#define WPc     63
#define NWc     81
#define BATCH   8
#define TOKP    (BATCH*HPc*WPc)   // 31752 windowed rows
#define TOKC    (BATCH*60*60)     // 28800 cropped tokens
#define MLPH    1536
#define TPB     3969              // windowed rows per batch
#define CONVK   3456              // 384*9
#define CONVN   192

typedef __attribute__((ext_vector_type(8))) short short8;
typedef __attribute__((ext_vector_type(4))) float f32x4;
typedef unsigned short u16;

__device__ __forceinline__ u16 f2bf(float f) {
  unsigned u = __float_as_uint(f);
  u += 0x7fff + ((u >> 16) & 1);           // RNE
  return (u16)(u >> 16);
}
__device__ __forceinline__ float bf2f(u16 b) { return __uint_as_float((unsigned)b << 16); }

// global -> LDS async 16B: dest = wave-uniform base + lane*16; src per-lane
#define GLOAD16(gp, lp) __builtin_amdgcn_global_load_lds( \
    (const __attribute__((address_space(1))) unsigned*)(gp), \
    (__attribute__((address_space(3))) unsigned*)(lp), 16, 0, 0)

// bijective XCD swizzle (m204)
__device__ __forceinline__ int xcd_swizzle(int orig, int nwg) {
  int q = nwg >> 3, r = nwg & 7;
  int xcd = orig & 7, off = orig >> 3;
  return (xcd < r ? xcd*(q+1) : r*(q+1) + (xcd - r)*q) + off;
}

// ---------------- block reduce (384 threads, 6 waves) ----------------
__device__ __forceinline__ float2 block_reduce_384(float v, float* red) {
  __syncthreads();
  float s = v, q = v * v;
  #pragma unroll
  for (int o = 32; o > 0; o >>= 1) {
    s += __shfl_down(s, o);
    q += __shfl_down(q, o);
  }
  int w = threadIdx.x >> 6;
  if ((threadIdx.x & 63) == 0) { red[2*w] = s; red[2*w+1] = q; }
  __syncthreads();
  float ts = red[0]+red[2]+red[4]+red[6]+red[8]+red[10];
  float tq = red[1]+red[3]+red[5]+red[7]+red[9]+red[11];
  return make_float2(ts, tq);
}

// ---------------- K1a ----------------
__global__ __launch_bounds__(384)
void k1a_kernel(const float* __restrict__ x, const float* __restrict__ g,
                const float* __restrict__ nw, const float* __restrict__ nb,
                const float* __restrict__ n1w, const float* __restrict__ n1b,
                float* __restrict__ musig, u16* __restrict__ wbuf)
{
  __shared__ float red[12];
  int t = blockIdx.x;
  int b = t / (HPc*WPc);
  int rem = t - b*(HPc*WPc);
  int i = rem / WPc, j = rem - (rem / WPc)*WPc;
  int c = threadIdx.x;

  float v = 0.f;
  if (i < 60 && j < 60) {
    if (c < 192) v = x[(((size_t)b*192 + c)*60 + i)*60 + j];
    else         v = g[(((size_t)b*192 + (c-192))*60 + i)*60 + j];
  }
  float2 ss = block_reduce_384(v, red);
  float mu  = ss.x * (1.f/384.f);
  float var = ss.y * (1.f/384.f) - mu*mu;
  float rs  = rsqrtf(var + 1e-5f);
  if (c == 0) { musig[2*t] = mu; musig[2*t+1] = rs; }
  float zi  = (v - mu) * rs * nw[c] + nb[c];
  float2 s2 = block_reduce_384(zi, red);
  float mu2  = s2.x * (1.f/384.f);
  float var2 = s2.y * (1.f/384.f) - mu2*mu2;
  float zn = (zi - mu2) * rsqrtf(var2 + 1e-5f) * n1w[c] + n1b[c];
  int ai = i - 3; if (ai < 0) ai += HPc;
  int aj = j - 3; if (aj < 0) aj += WPc;
  int win = (ai/7)*9 + (aj/7);
  int tok = (ai%7)*7 + (aj%7);
  wbuf[(((size_t)b*NWc + win)*49 + tok)*C2c + c] = f2bf(zn);
}

// ---------------- K1b ----------------
__global__ __launch_bounds__(384)
void k1b_kernel(const float* __restrict__ x, const float* __restrict__ g,
                const float* __restrict__ nw, const float* __restrict__ nb,
                const float* __restrict__ musig, float* __restrict__ z)
{
  int tc = blockIdx.x;
  int b = tc / 3600;
  int rem = tc - b*3600;
  int i = rem / 60, j = rem - (rem/60)*60;
  int t = b*(HPc*WPc) + i*WPc + j;
  int c = threadIdx.x;
  float v;
  if (c < 192) v = x[(((size_t)b*192 + c)*60 + i)*60 + j];
  else         v = g[(((size_t)b*192 + (c-192))*60 + i)*60 + j];
  float mu = musig[2*t], rs = musig[2*t+1];
  z[(size_t)tc*C2c + c] = (v - mu) * rs * nw[c] + nb[c];
}

// ---------------- LN (n2) ----------------
__global__ __launch_bounds__(384)
void ln2_kernel(const float* __restrict__ z, const float* __restrict__ nw,
                const float* __restrict__ nb, u16* __restrict__ out)
{
  __shared__ float red[12];
  int tc = blockIdx.x;
  int c = threadIdx.x;
  float v = z[(size_t)tc*C2c + c];
  float2 ss = block_reduce_384(v, red);
  float mu  = ss.x * (1.f/384.f);
  float var = ss.y * (1.f/384.f) - mu*mu;
  out[(size_t)tc*C2c + c] = f2bf((v - mu) * rsqrtf(var + 1e-5f) * nw[c] + nb[c]);
}

// ---------------- fp32 -> bf16 bulk convert (weight casts) ----------------
__global__ __launch_bounds__(256)
void f2bf_kernel(const float* __restrict__ in, u16* __restrict__ out, int n4)
{
  int t = blockIdx.x*256 + threadIdx.x;
  if (t >= n4) return;
  float4 v = ((const float4*)in)[t];
  ushort4 o;
  o.x = f2bf(v.x); o.y = f2bf(v.y); o.z = f2bf(v.z); o.w = f2bf(v.w);
  ((ushort4*)out)[t] = o;
}

__global__ void zero_kernel(uint4* p) { p[threadIdx.x] = make_uint4(0,0,0,0); }

// conv weight: transpose OIHW -> [oc][p*384+c], split hi/lo
__global__ void split_convw(const float* __restrict__ cw, u16* __restrict__ hi, u16* __restrict__ lo)
{
  int t = blockIdx.x*blockDim.x + threadIdx.x;
  if (t >= CONVN*CONVK) return;
  int oc = t / CONVK, k = t - oc*CONVK;
  int p = k / 384, c = k - p*384;
  float v = cw[((size_t)oc*384 + c)*9 + p];
  u16 h = f2bf(v);
  hi[t] = h;
  lo[t] = f2bf(v - bf2f(h));
}

// ---------------- MFMA GEMM (128x128, BK=64, single bf16 weight, XCD swizzle) ----------------
// EPI 0: bf16 store  EPI 1: z scatter-add (proj)  EPI 2: GELU bf16 (fc1)
// EPI 3: z += val(+bias)  EPI 4: vv = val+bias+z; z=vv; Cb=bf16(vv)
template<int EPI>
__global__ __launch_bounds__(256)
void mfma_gemm(const u16* __restrict__ A, const u16* __restrict__ B,
               const float* __restrict__ bias, u16* __restrict__ Cb, float* __restrict__ zbuf,
               int M, int N, int K, int ldb, int addbias)
{
  __shared__ u16 As [128*64];
  __shared__ u16 Bs [128*64];
  int tid = threadIdx.x;
  int lane = tid & 63, w = tid >> 6;
  int wr = w >> 1, wc = w & 1;
  int nwg = gridDim.x * gridDim.y;
  int swz = xcd_swizzle(blockIdx.y*gridDim.x + blockIdx.x, nwg);
  int bx = swz % gridDim.x, by = swz / gridDim.x;
  int m0 = by * 128, n0 = bx * 128;
  int srow = lane >> 3, sslot = (lane & 7) ^ srow;

  f32x4 acc[4][4];
  #pragma unroll
  for (int i = 0; i < 4; ++i)
    #pragma unroll
    for (int j = 0; j < 4; ++j) acc[i][j] = (f32x4){0.f,0.f,0.f,0.f};

  char* AsB = (char*)As; char* BsB = (char*)Bs;
  int r15 = lane & 15, kq = lane >> 4;

  for (int k0 = 0; k0 < K; k0 += 64) {
    #pragma unroll
    for (int i = 0; i < 4; ++i) {
      int rblk = w*4 + i;
      int ar = m0 + rblk*8 + srow; if (ar >= M) ar = M - 1;
      int br = n0 + rblk*8 + srow;
      GLOAD16(A + (size_t)ar*K   + k0 + sslot*8, AsB + rblk*1024);
      GLOAD16(B + (size_t)br*ldb + k0 + sslot*8, BsB + rblk*1024);
    }
    __syncthreads();
    #pragma unroll
    for (int ks = 0; ks < 2; ++ks) {
      int slog = ks*4 + kq;
      short8 af[4], bf[4];
      #pragma unroll
      for (int mi = 0; mi < 4; ++mi) {
        int row = wr*64 + mi*16 + r15;
        af[mi] = *(const short8*)(AsB + row*128 + ((slog ^ (row&7))<<4));
      }
      #pragma unroll
      for (int ni = 0; ni < 4; ++ni) {
        int row = wc*64 + ni*16 + r15;
        bf[ni] = *(const short8*)(BsB + row*128 + ((slog ^ (row&7))<<4));
      }
      #pragma unroll
      for (int mi = 0; mi < 4; ++mi)
        #pragma unroll
        for (int ni = 0; ni < 4; ++ni)
          acc[mi][ni] = __builtin_amdgcn_mfma_f32_16x16x32_bf16(af[mi], bf[ni], acc[mi][ni], 0, 0, 0);
    }
    __syncthreads();
  }

  int fq = lane >> 4, fr = lane & 15;
  #pragma unroll
  for (int mi = 0; mi < 4; ++mi) {
    #pragma unroll
    for (int j = 0; j < 4; ++j) {
      int m = m0 + wr*64 + mi*16 + fq*4 + j;
      if (m >= M) continue;
      int zrow = 0; bool zok = true;
      if (EPI == 1) {
        int b = m / TPB;
        int rem = m - b*TPB;
        int win = rem / 49, tok = rem - (rem/49)*49;
        int wh = win/9, ww = win - (win/9)*9;
        int th = tok/7, tw = tok - (tok/7)*7;
        int oi = wh*7 + th + 3; if (oi >= HPc) oi -= HPc;
        int oj = ww*7 + tw + 3; if (oj >= WPc) oj -= WPc;
        zok = (oi < 60 && oj < 60);
        zrow = (b*60 + oi)*60 + oj;
      }
      #pragma unroll
      for (int ni = 0; ni < 4; ++ni) {
        int n = n0 + wc*64 + ni*16 + fr;
        float val = acc[mi][ni][j];
        if (EPI == 0) {
          Cb[(size_t)m*N + n] = f2bf(val + bias[n]);
        } else if (EPI == 1) {
          if (zok) zbuf[(size_t)zrow*C2c + n] += val + bias[n];
        } else if (EPI == 2) {
          float vv = val + bias[n];
          float ge = 0.5f*vv*(1.f + erff(vv*0.70710678118654752f));
          Cb[(size_t)m*N + n] = f2bf(ge);
        } else if (EPI == 3) {
          float vv = val + (addbias ? bias[n] : 0.f);
          zbuf[(size_t)m*C2c + n] += vv;
        } else { // EPI == 4
          float vv = val + (addbias ? bias[n] : 0.f) + zbuf[(size_t)m*C2c + n];
          zbuf[(size_t)m*C2c + n] = vv;
          Cb[(size_t)m*C2c + n] = f2bf(vv);
        }
      }
    }
  }
}

// ---------------- conv im2col MFMA: BM=64, BN=64, BK=128, hi/lo, all-gload_lds staging ----------------
__global__ __launch_bounds__(256)
void mfma_conv(const u16* __restrict__ Y, const u16* __restrict__ Bh, const u16* __restrict__ Bl,
               const float* __restrict__ cb, const float* __restrict__ xres,
               const u16* __restrict__ zpad, float* __restrict__ outp)
{
  __shared__ u16 As [64*128];   // 16 KB, row stride 256 B (16 slots of 16 B)
  __shared__ u16 Bsh[64*128];   // 16 KB
  __shared__ u16 Bsl[64*128];   // 16 KB -> 48 KB total
  int tid = threadIdx.x;
  int lane = tid & 63, w = tid >> 6;
  int wr = w >> 1, wc = w & 1;
  int nwg = gridDim.x * gridDim.y;   // 3*450 = 1350
  int swz = xcd_swizzle(blockIdx.y*gridDim.x + blockIdx.x, nwg);
  int bx = swz % 3, by = swz / 3;
  int m0 = by * 64, n0 = bx * 64;
  int l4 = lane >> 4;                // row-within-4-row-chunk

  f32x4 acc[2][2];
  #pragma unroll
  for (int i = 0; i < 2; ++i)
    #pragma unroll
    for (int j = 0; j < 2; ++j) acc[i][j] = (f32x4){0.f,0.f,0.f,0.f};

  // hoist per-(thread, chunk) A coords: wave w stages A chunks {w, w+4, w+8, w+12}
  int pbA[4], ohA[4], owA[4], ssA[4], cA[4];
  #pragma unroll
  for (int i = 0; i < 4; ++i) {
    cA[i] = i*4 + w;
    int row = cA[i]*4 + l4;
    int pix = m0 + row;
    int pb = pix / 3600;
    int prem = pix - pb*3600;
    pbA[i] = pb; ohA[i] = prem / 60; owA[i] = prem - (prem/60)*60;
    ssA[i] = (lane & 15) ^ (row & 7);      // pre-swizzled source slot
  }
  // B chunks: wave w stages {w, w+4, w+8, w+12}
  int brB[4], ssB[4], cB[4];
  #pragma unroll
  for (int j = 0; j < 4; ++j) {
    cB[j] = j*4 + w;
    int row = cB[j]*4 + l4;
    brB[j] = n0 + row;                     // always < 192
    ssB[j] = (lane & 15) ^ (row & 7);
  }

  char* AsB = (char*)As; char* BhB = (char*)Bsh; char* BlB = (char*)Bsl;
  int r15 = lane & 15, kq = lane >> 4;

  for (int k0 = 0; k0 < CONVK; k0 += 128) {
    int p  = k0 / 384;                 // tap constant within BK=128 (384 % 128 == 0)
    int c0 = k0 - p*384;
    int dh = p/3 - 1, dw = (p - (p/3)*3) - 1;
    #pragma unroll
    for (int j = 0; j < 4; ++j) {
      GLOAD16(Bh + (size_t)brB[j]*CONVK + k0 + ssB[j]*8, BhB + cB[j]*1024);
      GLOAD16(Bl + (size_t)brB[j]*CONVK + k0 + ssB[j]*8, BlB + cB[j]*1024);
    }
    #pragma unroll
    for (int i = 0; i < 4; ++i) {
      int ih = ohA[i] + dh, iw = owA[i] + dw;
      const u16* src = ((unsigned)ih < 60u && (unsigned)iw < 60u)
        ? Y + ((size_t)pbA[i]*3600 + ih*60 + iw)*C2c + c0 + ssA[i]*8
        : zpad;
      GLOAD16(src, AsB + cA[i]*1024);
    }
    __syncthreads();
    #pragma unroll
    for (int ks = 0; ks < 4; ++ks) {
      int slog = ks*4 + kq;
      short8 af[2], bh[2], bl[2];
      #pragma unroll
      for (int mi = 0; mi < 2; ++mi) {
        int row = wr*32 + mi*16 + r15;
        af[mi] = *(const short8*)(AsB + row*256 + ((slog ^ (row&7))<<4));
      }
      #pragma unroll
      for (int ni = 0; ni < 2; ++ni) {
        int row = wc*32 + ni*16 + r15;
        int off = row*256 + ((slog ^ (row&7))<<4);
        bh[ni] = *(const short8*)(BhB + off);
        bl[ni] = *(const short8*)(BlB + off);
      }
      #pragma unroll
      for (int mi = 0; mi < 2; ++mi)
        #pragma unroll
        for (int ni = 0; ni < 2; ++ni) {
          acc[mi][ni] = __builtin_amdgcn_mfma_f32_16x16x32_bf16(af[mi], bh[ni], acc[mi][ni], 0, 0, 0);
          acc[mi][ni] = __builtin_amdgcn_mfma_f32_16x16x32_bf16(af[mi], bl[ni], acc[mi][ni], 0, 0, 0);
        }
    }
    __syncthreads();
  }

  int fq = lane >> 4, fr = lane & 15;
  #pragma unroll
  for (int mi = 0; mi < 2; ++mi) {
    #pragma unroll
    for (int j = 0; j < 4; ++j) {
      int m = m0 + wr*32 + mi*16 + fq*4 + j;          // pixel id < 28800
      int pb = m / 3600;
      int rem = m - pb*3600;
      int oh = rem / 60, ow = rem - (rem/60)*60;
      #pragma unroll
      for (int ni = 0; ni < 2; ++ni) {
        int oc = n0 + wc*32 + ni*16 + fr;             // < 192
        size_t oi = ((size_t)pb*192 + oc)*3600 + oh*60 + ow;
        outp[oi] = acc[mi][ni][j] + cb[oc] + xres[oi];
      }
    }
  }
}

// ---------------- windowed attention (register-tiled) ----------------
#define QS_STRIDE 100
#define VS_STRIDE 104
#define SS_STRIDE 53

__global__ __launch_bounds__(256)
void attn_kernel(const u16* __restrict__ qkv, const float* __restrict__ rpb,
                 u16* __restrict__ out)
{
  __shared__ float qs[52*QS_STRIDE];
  __shared__ float ks[52*QS_STRIDE];
  __shared__ float S[52*SS_STRIDE];
  int blk = blockIdx.x;
  int h   = blk & 3;
  int bw  = blk >> 2;
  int win = bw % NWc;
  const u16* base = qkv + (size_t)bw*49*1152;
  int tid = threadIdx.x;

  for (int t2 = tid; t2 < 588; t2 += 256) {
    int r = t2 / 12, dq = t2 - (t2/12)*12;
    short8 qv = *(const short8*)(base + r*1152 +       h*96 + dq*8);
    short8 kv = *(const short8*)(base + r*1152 + 384 + h*96 + dq*8);
    #pragma unroll
    for (int e = 0; e < 8; ++e) {
      qs[r*QS_STRIDE + dq*8 + e] = bf2f((u16)qv[e]);
      ks[r*QS_STRIDE + dq*8 + e] = bf2f((u16)kv[e]);
    }
  }
  __syncthreads();

  const float scale = 0.1020620726159657f;
  int wh = win / 9, ww = win - (win/9)*9;

  if (tid < 169) {
    int tr = tid / 13, tc = tid - (tid/13)*13;
    int r0 = tr*4, c0 = tc*4;
    float a[4][4] = {};
    for (int k0 = 0; k0 < 96; k0 += 4) {
      float4 qv[4], kv4[4];
      #pragma unroll
      for (int i = 0; i < 4; ++i) qv[i]  = *(const float4*)&qs[(r0+i)*QS_STRIDE + k0];
      #pragma unroll
      for (int j = 0; j < 4; ++j) kv4[j] = *(const float4*)&ks[(c0+j)*QS_STRIDE + k0];
      #pragma unroll
      for (int i = 0; i < 4; ++i)
        #pragma unroll
        for (int j = 0; j < 4; ++j)
          a[i][j] += qv[i].x*kv4[j].x + qv[i].y*kv4[j].y + qv[i].z*kv4[j].z + qv[i].w*kv4[j].w;
    }
    #pragma unroll
    for (int i = 0; i < 4; ++i) {
      int r = r0 + i;
      if (r < 49) {
        int r1 = r/7, c1 = r - (r/7)*7;
        int hp1 = wh*7 + r1, wp1 = ww*7 + c1;
        int g1 = (hp1 < 56 ? 0 : (hp1 < 60 ? 1 : 2))*3 + (wp1 < 56 ? 0 : (wp1 < 60 ? 1 : 2));
        #pragma unroll
        for (int j = 0; j < 4; ++j) {
          int c = c0 + j;
          if (c < 49) {
            int r2 = c/7, c2 = c - (c/7)*7;
            float s = a[i][j]*scale + rpb[((r1 - r2 + 6)*13 + (c1 - c2 + 6))*HEADS + h];
            int hp2 = wh*7 + r2, wp2 = ww*7 + c2;
            int g2 = (hp2 < 56 ? 0 : (hp2 < 60 ? 1 : 2))*3 + (wp2 < 56 ? 0 : (wp2 < 60 ? 1 : 2));
            if (g1 != g2) s -= 100.f;
            S[r*SS_STRIDE + c] = s;
          }
        }
      }
    }
  }
  __syncthreads();

  for (int t2 = tid; t2 < 588; t2 += 256) {
    int r = t2 / 12, dq = t2 - (t2/12)*12;
    short8 vv = *(const short8*)(base + r*1152 + 768 + h*96 + dq*8);
    #pragma unroll
    for (int e = 0; e < 8; ++e) ks[r*VS_STRIDE + dq*8 + e] = bf2f((u16)vv[e]);
  }
  if (tid < 49) {
    float mx = -1e30f;
    for (int c = 0; c < 49; ++c) mx = fmaxf(mx, S[tid*SS_STRIDE + c]);
    float sum = 0.f;
    for (int c = 0; c < 49; ++c) { float e = expf(S[tid*SS_STRIDE + c] - mx); S[tid*SS_STRIDE + c] = e; sum += e; }
    float inv = 1.f / sum;
    for (int c = 0; c < 49; ++c) S[tid*SS_STRIDE + c] *= inv;
  }
  __syncthreads();

  if (tid < 156) {
    int tr2 = tid / 12, tc2 = tid - (tid/12)*12;
    int r0 = tr2*4, d0 = tc2*8;
    float o[4][8] = {};
    for (int c = 0; c < 49; ++c) {
      float4 v0 = *(const float4*)&ks[c*VS_STRIDE + d0];
      float4 v1 = *(const float4*)&ks[c*VS_STRIDE + d0 + 4];
      #pragma unroll
      for (int i = 0; i < 4; ++i) {
        float sv = S[(r0+i)*SS_STRIDE + c];
        o[i][0] += sv*v0.x; o[i][1] += sv*v0.y; o[i][2] += sv*v0.z; o[i][3] += sv*v0.w;
        o[i][4] += sv*v1.x; o[i][5] += sv*v1.y; o[i][6] += sv*v1.z; o[i][7] += sv*v1.w;
      }
    }
    #pragma unroll
    for (int i = 0; i < 4; ++i) {
      int r = r0 + i;
      if (r >= 49) continue;
      ushort4 w0, w1;
      w0.x = f2bf(o[i][0]); w0.y = f2bf(o[i][1]); w0.z = f2bf(o[i][2]); w0.w = f2bf(o[i][3]);
      w1.x = f2bf(o[i][4]); w1.y = f2bf(o[i][5]); w1.z = f2bf(o[i][6]); w1.w = f2bf(o[i][7]);
      size_t ob = ((size_t)bw*49 + r)*C2c + h*96 + d0;
      *(ushort4*)&out[ob]     = w0;
      *(ushort4*)&out[ob + 4] = w1;
    }
  }
}

// ---------------- host launcher ----------------
extern "C" void kernel_launch(void* const* d_in, const int* in_sizes, int n_in,
                              void* d_out, int out_size, void* d_ws, size_t ws_size,
                              hipStream_t stream)
{
  const float* x      = (const float*)d_in[0];
  const float* g      = (const float*)d_in[1];
  const float* norm_w = (const float*)d_in[2];
  const float* norm_b = (const float*)d_in[3];
  const float* n1_w   = (const float*)d_in[4];
  const float* n1_b   = (const float*)d_in[5];
  const float* qkv_w  = (const float*)d_in[6];
  const float* qkv_b  = (const float*)d_in[7];
  const float* proj_w = (const float*)d_in[8];
  const float* proj_b = (const float*)d_in[9];
  const float* rpb    = (const float*)d_in[10];
  const float* n2_w   = (const float*)d_in[11];
  const float* n2_b   = (const float*)d_in[12];
  const float* fc1_w  = (const float*)d_in[13];
  const float* fc1_b  = (const float*)d_in[14];
  const float* fc2_w  = (const float*)d_in[15];
  const float* fc2_b  = (const float*)d_in[16];
  const float* conv_w = (const float*)d_in[17];
  const float* conv_b = (const float*)d_in[18];
  float* outp = (float*)d_out;

  // ---- workspace layout (qkvw placed right after qr: dead in phase 2, hid_c may overrun into it) ----
  char* p = (char*)d_ws;
  u16* wbuf = (u16*)p;              p += (size_t)TOKP*C2c*2;        // 24.39 MB
  char* qr  = p;                    p += (size_t)TOKP*1152*2;       // 73.16 MB qkv bf16 (phase 1)
  u16*   qkvb = (u16*)qr;
  float* z    = (float*)qr;                                          // 44.24 MB fp32 residual (phase 2)
  u16*   hid_c = (u16*)(qr + (size_t)TOKC*C2c*4);                    // 29.49 MB chunk hidden (overruns into qkvw)
  u16* qkvw = (u16*)p; p += 442368*2;                                // dead after qkv GEMM
  u16* pw   = (u16*)p; p += 147456*2;
  u16* f1w  = (u16*)p; p += 589824*2;
  u16* f2w  = (u16*)p; p += 589824*2;
  u16* cvwh = (u16*)p; p += (size_t)CONVN*CONVK*2;
  u16* cvwl = (u16*)p; p += (size_t)CONVN*CONVK*2;
  float* musig = (float*)p; p += (size_t)TOKP*2*4;
  u16* zpad = (u16*)p; p += 256;                                     // zero pad for conv OOB taps
  u16* hid_f = (u16*)p;                                              // full hidden (88.5 MB) if ws allows
  size_t need_full = (size_t)(p - (char*)d_ws) + (size_t)TOKC*MLPH*2;
  bool full_mlp = ws_size >= need_full;

  // weight casts + conv split + zero pad
  f2bf_kernel<<<(442368/4 + 255)/256, 256, 0, stream>>>(qkv_w, qkvw, 442368/4);
  f2bf_kernel<<<(147456/4 + 255)/256, 256, 0, stream>>>(proj_w, pw, 147456/4);
  f2bf_kernel<<<(589824/4 + 255)/256, 256, 0, stream>>>(fc1_w, f1w, 589824/4);
  f2bf_kernel<<<(589824/4 + 255)/256, 256, 0, stream>>>(fc2_w, f2w, 589824/4);
  split_convw<<<(CONVN*CONVK + 255)/256, 256, 0, stream>>>(conv_w, cvwh, cvwl);
  zero_kernel<<<1, 16, 0, stream>>>((uint4*)zpad);

  // K1a
  k1a_kernel<<<TOKP, 384, 0, stream>>>(x, g, norm_w, norm_b, n1_w, n1_b, musig, wbuf);

  // qkv GEMM
  mfma_gemm<0><<<dim3(9, 249), 256, 0, stream>>>(
      wbuf, qkvw, qkv_b, qkvb, nullptr, TOKP, 1152, 384, 384, 1);

  // attention
  attn_kernel<<<BATCH*NWc*HEADS, 256, 0, stream>>>(qkvb, rpb, wbuf);

  // K1b: rebuild fp32 residual z
  k1b_kernel<<<TOKC, 384, 0, stream>>>(x, g, norm_w, norm_b, musig, z);

  // proj GEMM + scatter-add into z
  mfma_gemm<1><<<dim3(3, 249), 256, 0, stream>>>(
      wbuf, pw, proj_b, nullptr, z, TOKP, 384, 384, 384, 1);

  // LN (n2)
  ln2_kernel<<<TOKC, 384, 0, stream>>>(z, n2_w, n2_b, wbuf);

  if (full_mlp) {
    mfma_gemm<2><<<dim3(12, 225), 256, 0, stream>>>(
        wbuf, f1w, fc1_b, hid_f, nullptr, TOKC, MLPH, 384, 384, 1);
    mfma_gemm<4><<<dim3(3, 225), 256, 0, stream>>>(
        hid_f, f2w, fc2_b, wbuf, z, TOKC, 384, MLPH, MLPH, 1);
  } else {
    // M-chunked MLP: 3 chunks of 9600 tokens, full hidden width, z RMW once
    const int CH = 9600;   // 75 * 128
    for (int off = 0; off < TOKC; off += CH) {
      mfma_gemm<2><<<dim3(12, 75), 256, 0, stream>>>(
          wbuf + (size_t)off*C2c, f1w, fc1_b, hid_c, nullptr, CH, MLPH, 384, 384, 1);
      mfma_gemm<4><<<dim3(3, 75), 256, 0, stream>>>(
          hid_c, f2w, fc2_b, wbuf + (size_t)off*C2c, z + (size_t)off*C2c, CH, 384, MLPH, MLPH, 1);
    }
  }

  // conv 3x3 im2col MFMA (BM=64, BN=64, BK=128, all-gload_lds) + conv_b + x residual
  mfma_conv<<<dim3(3, 450), 256, 0, stream>>>(wbuf, cvwh, cvwl, conv_b, x, zpad, outp);
}